// Round 8
// baseline (299.527 us; speedup 1.0000x reference)
//
#include <hip/hip_runtime.h>
#include <hip/hip_fp16.h>

#define NN 40000
#define EE 640000
#define NCH 157   // ceil(NN/256)

typedef unsigned int uint;
typedef unsigned short ushort;
typedef __attribute__((ext_vector_type(8))) short short8;
typedef __attribute__((ext_vector_type(4))) float floatx4;
typedef __attribute__((ext_vector_type(4))) uint uint4e;

// ---- bf16 helpers (RNE) ----
__device__ inline ushort f2bf(float f) {
    uint u = __float_as_uint(f);
    return (ushort)((u + 0x7fffu + ((u >> 16) & 1u)) >> 16);
}
__device__ inline float bf_lo(uint u) { return __uint_as_float(u << 16); }
__device__ inline float bf_hi(uint u) { return __uint_as_float(u & 0xffff0000u); }

__device__ inline int lower_bound_dev(const int* __restrict__ a, int n, int x) {
    int lo = 0, hi = n;
    while (lo < hi) { int m = (lo + hi) >> 1; if (a[m] < x) lo = m + 1; else hi = m; }
    return lo;
}

// ---------------- hist + weight prep + graph bounds (one launch) ----------------
__global__ __launch_bounds__(256) void histprep_kernel(const int* __restrict__ dst,
                                                       int* __restrict__ counts,
                                                       const float* __restrict__ W_in,
                                                       const float* __restrict__ W1,
                                                       const float* __restrict__ b_in,
                                                       const float* __restrict__ W2,
                                                       const int* __restrict__ batch,
                                                       ushort* __restrict__ Bp1,
                                                       ushort* __restrict__ Bp2,
                                                       float* __restrict__ cvec,
                                                       int* __restrict__ glo) {
    int b = blockIdx.x, t = threadIdx.x;
    if (b < 2500) {
        atomicAdd(&counts[dst[b * 256 + t]], 1);
    } else if (b < 2564) {
        int idx = (b - 2500) * 256 + t;
        int k = idx >> 7, n = idx & 127;
        float s = 0.f;
        for (int j = 0; j < 128; ++j) s = fmaf(W_in[k * 128 + j], W1[j * 128 + n], s);
        Bp1[((size_t)(k >> 3) * 128 + n) * 8 + (k & 7)] = f2bf(s);
    } else if (b < 2628) {
        int idx = (b - 2564) * 256 + t;
        int k = idx >> 7, n = idx & 127;
        Bp2[((size_t)(k >> 3) * 128 + n) * 8 + (k & 7)] = f2bf(W2[idx]);
    } else {
        if (t < 128) {
            float s = 0.f;
            for (int k = 0; k < 128; ++k) s = fmaf(b_in[k], W1[k * 128 + t], s);
            cvec[t] = s;
        } else if (t < 128 + 17) {
            int g = t - 128;                      // 0..16
            glo[g] = lower_bound_dev(batch, NN, g);
        }
    }
}

// ---------------- single-pass CSR offsets + spack ----------------
// spack[i] = i | fp16(dis[i])<<16 — the per-edge payload is just spack[src].
__global__ __launch_bounds__(256) void scan_kernel(const int* __restrict__ counts,
                                                   int* __restrict__ goff,
                                                   int* __restrict__ start,
                                                   int* __restrict__ cursor,
                                                   float* __restrict__ dis,
                                                   uint* __restrict__ spack, int N) {
    __shared__ int ws[4];
    __shared__ int sbase;
    int t = threadIdx.x, lane = t & 63, wv = t >> 6;
    int idx = blockIdx.x * 256 + t;
    int c = (idx < N) ? counts[idx] : 0;
    int v = c;
    #pragma unroll
    for (int d = 1; d < 64; d <<= 1) {
        int u = __shfl_up(v, d, 64);
        if (lane >= d) v += u;
    }
    if (lane == 63) ws[wv] = v;
    __syncthreads();
    if (t == 0) {
        int total = ws[0] + ws[1] + ws[2] + ws[3];
        sbase = atomicAdd(goff, total);
    }
    __syncthreads();
    int off = sbase;
    for (int j = 0; j < wv; ++j) off += ws[j];
    if (idx < N) {
        int excl = off + v - c;
        start[idx] = excl;
        cursor[idx] = excl;
        float dv = rsqrtf((float)c + 1.0f);
        dis[idx] = dv;
        spack[idx] = (uint)idx | ((uint)__half_as_ushort(__float2half_rn(dv)) << 16);
    }
}

// ---- MFMA 64-row tile: C[64,128](bf16) = A[64,128] @ Bpack (row-major C) ----
template <bool ABF16>
__device__ inline void mm_tile(const void* __restrict__ Av, const ushort* __restrict__ Bpack,
                               ushort* __restrict__ C, int tile, int wv, int lane) {
    int m = lane & 15, q = lane >> 4;
    int row = tile * 64 + wv * 16 + m;

    short8 afr[4];
    if (ABF16) {
        const ushort* A = (const ushort*)Av;
        const ushort* ap = A + (size_t)row * 128 + q * 8;
        #pragma unroll
        for (int k0 = 0; k0 < 4; ++k0) afr[k0] = *(const short8*)(ap + k0 * 32);
    } else {
        const float* A = (const float*)Av;
        const float* ap = A + (size_t)row * 128 + q * 8;
        #pragma unroll
        for (int k0 = 0; k0 < 4; ++k0) {
            float4 f0 = *(const float4*)(ap + k0 * 32);
            float4 f1 = *(const float4*)(ap + k0 * 32 + 4);
            short8 a;
            a[0] = (short)f2bf(f0.x); a[1] = (short)f2bf(f0.y);
            a[2] = (short)f2bf(f0.z); a[3] = (short)f2bf(f0.w);
            a[4] = (short)f2bf(f1.x); a[5] = (short)f2bf(f1.y);
            a[6] = (short)f2bf(f1.z); a[7] = (short)f2bf(f1.w);
            afr[k0] = a;
        }
    }

    floatx4 acc[8];
    #pragma unroll
    for (int nt = 0; nt < 8; ++nt) { floatx4 z = {0.f, 0.f, 0.f, 0.f}; acc[nt] = z; }

    #pragma unroll
    for (int nt = 0; nt < 8; ++nt) {
        #pragma unroll
        for (int k0 = 0; k0 < 4; ++k0) {
            short8 bfrag = *(const short8*)(Bpack + ((size_t)(k0 * 4 + q) * 128 + nt * 16 + m) * 8);
            acc[nt] = __builtin_amdgcn_mfma_f32_16x16x32_bf16(afr[k0], bfrag, acc[nt], 0, 0, 0);
        }
    }

    int orow_base = tile * 64 + wv * 16 + q * 4;
    #pragma unroll
    for (int nt = 0; nt < 8; ++nt) {
        #pragma unroll
        for (int r = 0; r < 4; ++r)
            C[(size_t)(orow_base + r) * 128 + nt * 16 + m] = f2bf(acc[nt][r]);
    }
}

// ---------------- fill CSR ∪ mm1 (independent, one launch) ----------------
// edata entry = spack[src]: low 16 = src id, high 16 = fp16 dis[src].
// dis[dst] is factored out of the edge loop (applied once per node in agg).
__global__ __launch_bounds__(256) void fillmm1_kernel(const int* __restrict__ src,
                                                      const int* __restrict__ dst,
                                                      const uint* __restrict__ spack,
                                                      int* __restrict__ cursor,
                                                      uint* __restrict__ edata,
                                                      const float* __restrict__ x,
                                                      const ushort* __restrict__ Bp1,
                                                      ushort* __restrict__ bufA) {
    int b = blockIdx.x, t = threadIdx.x;
    if (b < 2500) {
        int e = b * 256 + t;
        int s = src[e], d = dst[e];
        int pos = atomicAdd(&cursor[d], 1);
        edata[pos] = spack[s];
    } else {
        mm_tile<false>(x, Bp1, bufA, b - 2500, t >> 6, t & 63);
    }
}

// ---------------- layer-1: aggregation fused with @W2 (MFMA from LDS A-tile) ----
// 2500 blocks x 256 threads. Each of 4 waves gathers 4 consecutive dst nodes ->
// 16-row bf16 A-tile in LDS (16B slots, XOR swizzle slot ^= row&7, same key
// write/read). After one barrier each wave computes 2 of 8 column-tiles.
// Edge weights are fp16(dis[s]); dis[i] is applied once after the fold.
__global__ __launch_bounds__(256) void agg1m_kernel(const ushort* __restrict__ hw,
                                                    const float* __restrict__ dis,
                                                    const int* __restrict__ start,
                                                    const int* __restrict__ counts,
                                                    const uint* __restrict__ edata,
                                                    const float* __restrict__ cvec,
                                                    const float* __restrict__ bias,
                                                    const ushort* __restrict__ Bp2,
                                                    ushort* __restrict__ C) {
    __shared__ ushort Atile[16][128];   // 4 KB, swizzled 16B slots
    __shared__ uint eds[4][64];
    int t = threadIdx.x;
    int wv = t >> 6, lane = t & 63;
    int qg = lane & 15, h4 = lane >> 4;   // gather roles
    const uint4* __restrict__ hv4 = (const uint4*)hw;
    int base = blockIdx.x * 16;
    char* abase = (char*)&Atile[0][0];

    for (int n = 0; n < 4; ++n) {
        int nl = wv * 4 + n;              // local row 0..15
        int i = base + nl;
        int beg = start[i];
        int deg = counts[i];
        int dmain = deg > 64 ? 64 : deg;

        uint ed;
        if (lane < dmain) ed = edata[beg + lane];
        else ed = (uint)i;                // pad: self row, fp16 norm bits = 0
        eds[wv][lane] = ed;

        float a0 = 0.f, a1 = 0.f, a2 = 0.f, a3 = 0.f;
        float a4 = 0.f, a5 = 0.f, a6 = 0.f, a7 = 0.f;
        float sn = 0.f;

        int dpad = (dmain + 15) & ~15;
        for (int j = 0; j < dpad; j += 16) {
            uint e0 = eds[wv][j + h4];
            uint e1 = eds[wv][j + 4 + h4];
            uint e2 = eds[wv][j + 8 + h4];
            uint e3 = eds[wv][j + 12 + h4];
            uint4 u0 = hv4[(size_t)(e0 & 0xffffu) * 16 + qg];
            uint4 u1 = hv4[(size_t)(e1 & 0xffffu) * 16 + qg];
            uint4 u2 = hv4[(size_t)(e2 & 0xffffu) * 16 + qg];
            uint4 u3 = hv4[(size_t)(e3 & 0xffffu) * 16 + qg];
            float n0 = __half2float(__ushort_as_half((ushort)(e0 >> 16)));
            float n1 = __half2float(__ushort_as_half((ushort)(e1 >> 16)));
            float n2 = __half2float(__ushort_as_half((ushort)(e2 >> 16)));
            float n3 = __half2float(__ushort_as_half((ushort)(e3 >> 16)));
            a0 = fmaf(n0, bf_lo(u0.x), a0); a1 = fmaf(n0, bf_hi(u0.x), a1);
            a2 = fmaf(n0, bf_lo(u0.y), a2); a3 = fmaf(n0, bf_hi(u0.y), a3);
            a4 = fmaf(n0, bf_lo(u0.z), a4); a5 = fmaf(n0, bf_hi(u0.z), a5);
            a6 = fmaf(n0, bf_lo(u0.w), a6); a7 = fmaf(n0, bf_hi(u0.w), a7);
            a0 = fmaf(n1, bf_lo(u1.x), a0); a1 = fmaf(n1, bf_hi(u1.x), a1);
            a2 = fmaf(n1, bf_lo(u1.y), a2); a3 = fmaf(n1, bf_hi(u1.y), a3);
            a4 = fmaf(n1, bf_lo(u1.z), a4); a5 = fmaf(n1, bf_hi(u1.z), a5);
            a6 = fmaf(n1, bf_lo(u1.w), a6); a7 = fmaf(n1, bf_hi(u1.w), a7);
            a0 = fmaf(n2, bf_lo(u2.x), a0); a1 = fmaf(n2, bf_hi(u2.x), a1);
            a2 = fmaf(n2, bf_lo(u2.y), a2); a3 = fmaf(n2, bf_hi(u2.y), a3);
            a4 = fmaf(n2, bf_lo(u2.z), a4); a5 = fmaf(n2, bf_hi(u2.z), a5);
            a6 = fmaf(n2, bf_lo(u2.w), a6); a7 = fmaf(n2, bf_hi(u2.w), a7);
            a0 = fmaf(n3, bf_lo(u3.x), a0); a1 = fmaf(n3, bf_hi(u3.x), a1);
            a2 = fmaf(n3, bf_lo(u3.y), a2); a3 = fmaf(n3, bf_hi(u3.y), a3);
            a4 = fmaf(n3, bf_lo(u3.z), a4); a5 = fmaf(n3, bf_hi(u3.z), a5);
            a6 = fmaf(n3, bf_lo(u3.w), a6); a7 = fmaf(n3, bf_hi(u3.w), a7);
            sn += (n0 + n1) + (n2 + n3);
        }
        for (int e = beg + 64; e < beg + deg; ++e) {   // rare deg>64 tail
            uint et = edata[e];
            if (h4 == 0) {
                float n0 = __half2float(__ushort_as_half((ushort)(et >> 16)));
                uint4 u = hv4[(size_t)(et & 0xffffu) * 16 + qg];
                a0 = fmaf(n0, bf_lo(u.x), a0); a1 = fmaf(n0, bf_hi(u.x), a1);
                a2 = fmaf(n0, bf_lo(u.y), a2); a3 = fmaf(n0, bf_hi(u.y), a3);
                a4 = fmaf(n0, bf_lo(u.z), a4); a5 = fmaf(n0, bf_hi(u.z), a5);
                a6 = fmaf(n0, bf_lo(u.w), a6); a7 = fmaf(n0, bf_hi(u.w), a7);
                sn += n0;
            }
        }

        a0 += __shfl_xor(a0, 16); a0 += __shfl_xor(a0, 32);
        a1 += __shfl_xor(a1, 16); a1 += __shfl_xor(a1, 32);
        a2 += __shfl_xor(a2, 16); a2 += __shfl_xor(a2, 32);
        a3 += __shfl_xor(a3, 16); a3 += __shfl_xor(a3, 32);
        a4 += __shfl_xor(a4, 16); a4 += __shfl_xor(a4, 32);
        a5 += __shfl_xor(a5, 16); a5 += __shfl_xor(a5, 32);
        a6 += __shfl_xor(a6, 16); a6 += __shfl_xor(a6, 32);
        a7 += __shfl_xor(a7, 16); a7 += __shfl_xor(a7, 32);
        sn += __shfl_xor(sn, 16); sn += __shfl_xor(sn, 32);

        // apply dis[i] (factored out of edge loop), then self-loop term
        float di = dis[i];
        float sii = di * di;
        a0 *= di; a1 *= di; a2 *= di; a3 *= di;
        a4 *= di; a5 *= di; a6 *= di; a7 *= di;
        sn *= di;
        uint4 su = hv4[(size_t)i * 16 + qg];
        a0 = fmaf(sii, bf_lo(su.x), a0); a1 = fmaf(sii, bf_hi(su.x), a1);
        a2 = fmaf(sii, bf_lo(su.y), a2); a3 = fmaf(sii, bf_hi(su.y), a3);
        a4 = fmaf(sii, bf_lo(su.z), a4); a5 = fmaf(sii, bf_hi(su.z), a5);
        a6 = fmaf(sii, bf_lo(su.w), a6); a7 = fmaf(sii, bf_hi(su.w), a7);
        sn += sii;

        float4 ca = *(const float4*)(cvec + 8 * qg);
        float4 cb = *(const float4*)(cvec + 8 * qg + 4);
        float4 ba = *(const float4*)(bias + 8 * qg);
        float4 bb = *(const float4*)(bias + 8 * qg + 4);
        float o0 = fmaxf(fmaf(sn, ca.x, a0) + ba.x, 0.f);
        float o1 = fmaxf(fmaf(sn, ca.y, a1) + ba.y, 0.f);
        float o2 = fmaxf(fmaf(sn, ca.z, a2) + ba.z, 0.f);
        float o3 = fmaxf(fmaf(sn, ca.w, a3) + ba.w, 0.f);
        float o4 = fmaxf(fmaf(sn, cb.x, a4) + bb.x, 0.f);
        float o5 = fmaxf(fmaf(sn, cb.y, a5) + bb.y, 0.f);
        float o6 = fmaxf(fmaf(sn, cb.z, a6) + bb.z, 0.f);
        float o7 = fmaxf(fmaf(sn, cb.w, a7) + bb.w, 0.f);

        if (h4 == 0) {
            uint4e o;
            o.x = (uint)f2bf(o0) | ((uint)f2bf(o1) << 16);
            o.y = (uint)f2bf(o2) | ((uint)f2bf(o3) << 16);
            o.z = (uint)f2bf(o4) | ((uint)f2bf(o5) << 16);
            o.w = (uint)f2bf(o6) | ((uint)f2bf(o7) << 16);
            int slot = qg ^ (nl & 7);
            *(uint4e*)(abase + nl * 256 + slot * 16) = o;
        }
    }

    __syncthreads();

    {
        int m = lane & 15, qm = lane >> 4;
        short8 afr[4];
        #pragma unroll
        for (int k0 = 0; k0 < 4; ++k0) {
            int slot = (qm + 4 * k0) ^ (m & 7);
            afr[k0] = *(const short8*)(abase + m * 256 + slot * 16);
        }
        floatx4 acc[2];
        #pragma unroll
        for (int u = 0; u < 2; ++u) { floatx4 z = {0.f, 0.f, 0.f, 0.f}; acc[u] = z; }
        #pragma unroll
        for (int u = 0; u < 2; ++u) {
            int nt = 2 * wv + u;
            #pragma unroll
            for (int k0 = 0; k0 < 4; ++k0) {
                short8 bfrag = *(const short8*)(Bp2 + ((size_t)(k0 * 4 + qm) * 128 + nt * 16 + m) * 8);
                acc[u] = __builtin_amdgcn_mfma_f32_16x16x32_bf16(afr[k0], bfrag, acc[u], 0, 0, 0);
            }
        }
        int orow_base = base + qm * 4;
        #pragma unroll
        for (int u = 0; u < 2; ++u) {
            int nt = 2 * wv + u;
            #pragma unroll
            for (int r = 0; r < 4; ++r)
                C[(size_t)(orow_base + r) * 128 + nt * 16 + m] = f2bf(acc[u][r]);
        }
    }
}

// ---------------- GCN aggregation (layer 2): one wave per dst node ----------------
__global__ __launch_bounds__(256) void agg_kernel(const ushort* __restrict__ hw,
                                                  const float* __restrict__ dis,
                                                  const int* __restrict__ start,
                                                  const int* __restrict__ counts,
                                                  const uint* __restrict__ edata,
                                                  const float* __restrict__ cvec,
                                                  const float* __restrict__ bias,
                                                  ushort* __restrict__ out, int N) {
    __shared__ uint eds[4][64];
    int wv = threadIdx.x >> 6;
    int lane = threadIdx.x & 63;
    int q = lane & 15, h4 = lane >> 4;
    int i = blockIdx.x * 4 + wv;
    if (i >= N) return;
    int beg = start[i];
    int deg = counts[i];
    int dmain = deg > 64 ? 64 : deg;
    const uint4* __restrict__ hv4 = (const uint4*)hw;

    uint ed;
    if (lane < dmain) ed = edata[beg + lane];
    else ed = (uint)i;
    eds[wv][lane] = ed;

    float a0 = 0.f, a1 = 0.f, a2 = 0.f, a3 = 0.f;
    float a4 = 0.f, a5 = 0.f, a6 = 0.f, a7 = 0.f;
    float sn = 0.f;

    int dpad = (dmain + 15) & ~15;
    for (int j = 0; j < dpad; j += 16) {
        uint e0 = eds[wv][j + h4];
        uint e1 = eds[wv][j + 4 + h4];
        uint e2 = eds[wv][j + 8 + h4];
        uint e3 = eds[wv][j + 12 + h4];
        uint4 u0 = hv4[(size_t)(e0 & 0xffffu) * 16 + q];
        uint4 u1 = hv4[(size_t)(e1 & 0xffffu) * 16 + q];
        uint4 u2 = hv4[(size_t)(e2 & 0xffffu) * 16 + q];
        uint4 u3 = hv4[(size_t)(e3 & 0xffffu) * 16 + q];
        float n0 = __half2float(__ushort_as_half((ushort)(e0 >> 16)));
        float n1 = __half2float(__ushort_as_half((ushort)(e1 >> 16)));
        float n2 = __half2float(__ushort_as_half((ushort)(e2 >> 16)));
        float n3 = __half2float(__ushort_as_half((ushort)(e3 >> 16)));
        a0 = fmaf(n0, bf_lo(u0.x), a0); a1 = fmaf(n0, bf_hi(u0.x), a1);
        a2 = fmaf(n0, bf_lo(u0.y), a2); a3 = fmaf(n0, bf_hi(u0.y), a3);
        a4 = fmaf(n0, bf_lo(u0.z), a4); a5 = fmaf(n0, bf_hi(u0.z), a5);
        a6 = fmaf(n0, bf_lo(u0.w), a6); a7 = fmaf(n0, bf_hi(u0.w), a7);
        a0 = fmaf(n1, bf_lo(u1.x), a0); a1 = fmaf(n1, bf_hi(u1.x), a1);
        a2 = fmaf(n1, bf_lo(u1.y), a2); a3 = fmaf(n1, bf_hi(u1.y), a3);
        a4 = fmaf(n1, bf_lo(u1.z), a4); a5 = fmaf(n1, bf_hi(u1.z), a5);
        a6 = fmaf(n1, bf_lo(u1.w), a6); a7 = fmaf(n1, bf_hi(u1.w), a7);
        a0 = fmaf(n2, bf_lo(u2.x), a0); a1 = fmaf(n2, bf_hi(u2.x), a1);
        a2 = fmaf(n2, bf_lo(u2.y), a2); a3 = fmaf(n2, bf_hi(u2.y), a3);
        a4 = fmaf(n2, bf_lo(u2.z), a4); a5 = fmaf(n2, bf_hi(u2.z), a5);
        a6 = fmaf(n2, bf_lo(u2.w), a6); a7 = fmaf(n2, bf_hi(u2.w), a7);
        a0 = fmaf(n3, bf_lo(u3.x), a0); a1 = fmaf(n3, bf_hi(u3.x), a1);
        a2 = fmaf(n3, bf_lo(u3.y), a2); a3 = fmaf(n3, bf_hi(u3.y), a3);
        a4 = fmaf(n3, bf_lo(u3.z), a4); a5 = fmaf(n3, bf_hi(u3.z), a5);
        a6 = fmaf(n3, bf_lo(u3.w), a6); a7 = fmaf(n3, bf_hi(u3.w), a7);
        sn += (n0 + n1) + (n2 + n3);
    }
    for (int e = beg + 64; e < beg + deg; ++e) {
        uint et = edata[e];
        if (h4 == 0) {
            float n0 = __half2float(__ushort_as_half((ushort)(et >> 16)));
            uint4 u = hv4[(size_t)(et & 0xffffu) * 16 + q];
            a0 = fmaf(n0, bf_lo(u.x), a0); a1 = fmaf(n0, bf_hi(u.x), a1);
            a2 = fmaf(n0, bf_lo(u.y), a2); a3 = fmaf(n0, bf_hi(u.y), a3);
            a4 = fmaf(n0, bf_lo(u.z), a4); a5 = fmaf(n0, bf_hi(u.z), a5);
            a6 = fmaf(n0, bf_lo(u.w), a6); a7 = fmaf(n0, bf_hi(u.w), a7);
            sn += n0;
        }
    }

    a0 += __shfl_xor(a0, 16); a0 += __shfl_xor(a0, 32);
    a1 += __shfl_xor(a1, 16); a1 += __shfl_xor(a1, 32);
    a2 += __shfl_xor(a2, 16); a2 += __shfl_xor(a2, 32);
    a3 += __shfl_xor(a3, 16); a3 += __shfl_xor(a3, 32);
    a4 += __shfl_xor(a4, 16); a4 += __shfl_xor(a4, 32);
    a5 += __shfl_xor(a5, 16); a5 += __shfl_xor(a5, 32);
    a6 += __shfl_xor(a6, 16); a6 += __shfl_xor(a6, 32);
    a7 += __shfl_xor(a7, 16); a7 += __shfl_xor(a7, 32);
    sn += __shfl_xor(sn, 16); sn += __shfl_xor(sn, 32);

    // apply dis[i] (factored out of edge loop), then self-loop term
    float di = dis[i];
    float sii = di * di;
    a0 *= di; a1 *= di; a2 *= di; a3 *= di;
    a4 *= di; a5 *= di; a6 *= di; a7 *= di;
    sn *= di;
    uint4 su = hv4[(size_t)i * 16 + q];
    a0 = fmaf(sii, bf_lo(su.x), a0); a1 = fmaf(sii, bf_hi(su.x), a1);
    a2 = fmaf(sii, bf_lo(su.y), a2); a3 = fmaf(sii, bf_hi(su.y), a3);
    a4 = fmaf(sii, bf_lo(su.z), a4); a5 = fmaf(sii, bf_hi(su.z), a5);
    a6 = fmaf(sii, bf_lo(su.w), a6); a7 = fmaf(sii, bf_hi(su.w), a7);
    sn += sii;

    float c0 = 0.f, c1 = 0.f, c2 = 0.f, c3 = 0.f;
    float c4 = 0.f, c5 = 0.f, c6 = 0.f, c7 = 0.f;
    if (cvec) {
        float4 ca = *(const float4*)(cvec + 8 * q);
        float4 cb = *(const float4*)(cvec + 8 * q + 4);
        c0 = ca.x; c1 = ca.y; c2 = ca.z; c3 = ca.w;
        c4 = cb.x; c5 = cb.y; c6 = cb.z; c7 = cb.w;
    }
    float4 ba = *(const float4*)(bias + 8 * q);
    float4 bb = *(const float4*)(bias + 8 * q + 4);
    float o0 = fmaxf(fmaf(sn, c0, a0) + ba.x, 0.f);
    float o1 = fmaxf(fmaf(sn, c1, a1) + ba.y, 0.f);
    float o2 = fmaxf(fmaf(sn, c2, a2) + ba.z, 0.f);
    float o3 = fmaxf(fmaf(sn, c3, a3) + ba.w, 0.f);
    float o4 = fmaxf(fmaf(sn, c4, a4) + bb.x, 0.f);
    float o5 = fmaxf(fmaf(sn, c5, a5) + bb.y, 0.f);
    float o6 = fmaxf(fmaf(sn, c6, a6) + bb.z, 0.f);
    float o7 = fmaxf(fmaf(sn, c7, a7) + bb.w, 0.f);
    if (h4 == 0) {
        uint4 o;
        o.x = (uint)f2bf(o0) | ((uint)f2bf(o1) << 16);
        o.y = (uint)f2bf(o2) | ((uint)f2bf(o3) << 16);
        o.z = (uint)f2bf(o4) | ((uint)f2bf(o5) << 16);
        o.w = (uint)f2bf(o6) | ((uint)f2bf(o7) << 16);
        ((uint4*)out)[(size_t)i * 16 + q] = o;
    }
}

// ---------------- pool + final: branch-free per-(graph,chunk) blocks ----------------
// 1024 blocks (64 chunks/graph): enough waves in flight to stream 10 MB at
// full rate (128 blocks was latency-limited at ~600 GB/s). Last-arriving
// block (ticket 1023) runs the MLP head.
__global__ __launch_bounds__(256) void poolfinal_kernel(const ushort* __restrict__ h,
                                                        const int* __restrict__ glo,
                                                        float* __restrict__ pools,
                                                        int* __restrict__ ticket,
                                                        const float* __restrict__ Wf1,
                                                        const float* __restrict__ bf1,
                                                        const float* __restrict__ Wf2,
                                                        const float* __restrict__ bf2,
                                                        float* __restrict__ out) {
    __shared__ float pooled[16][128];
    __shared__ float z[16][64];
    __shared__ int slast;
    int t = threadIdx.x, c2 = t & 63, wv = t >> 6;
    int b = blockIdx.x;
    int g = b >> 6, ch = b & 63;
    int lo = glo[g], hi = glo[g + 1];
    int span = hi - lo;
    int chunk = (span + 63) >> 6;
    int r0 = lo + ch * chunk;
    int r1 = hi < r0 + chunk ? hi : r0 + chunk;
    const uint* __restrict__ hv = (const uint*)h;

    float a0 = 0.f, a1 = 0.f;
    #pragma unroll 4
    for (int j = r0 + wv; j < r1; j += 4) {
        uint u = hv[(size_t)j * 64 + c2];
        a0 += bf_lo(u);
        a1 += bf_hi(u);
    }
    if (r0 < r1) {
        atomicAdd(&pools[g * 128 + 2 * c2], a0);
        atomicAdd(&pools[g * 128 + 2 * c2 + 1], a1);
    }

    __syncthreads();
    __threadfence();
    if (t == 0) slast = atomicAdd(ticket, 1);
    __syncthreads();
    if (slast != 1023) return;

    for (int idx = t; idx < 2048; idx += 256) {
        int gg = idx >> 7, c = idx & 127;
        int cn = glo[gg + 1] - glo[gg];
        float cnf = (float)(cn > 1 ? cn : 1);
        float ps = __hip_atomic_load(&pools[idx], __ATOMIC_RELAXED, __HIP_MEMORY_SCOPE_AGENT);
        pooled[gg][c] = ps / cnf;
    }
    __syncthreads();
    for (int idx = t; idx < 1024; idx += 256) {
        int gg = idx >> 6, j = idx & 63;
        float s = bf1[j];
        for (int k = 0; k < 128; ++k) s = fmaf(pooled[gg][k], Wf1[k * 64 + j], s);
        z[gg][j] = fmaxf(s, 0.f);
    }
    __syncthreads();
    if (t < 160) {
        int gg = t / 10, k = t % 10;
        float s = bf2[k];
        for (int j = 0; j < 64; ++j) s = fmaf(z[gg][j], Wf2[j * 10 + k], s);
        out[t] = s;
    }
}

// ---------------- launch ----------------

extern "C" void kernel_launch(void* const* d_in, const int* in_sizes, int n_in,
                              void* d_out, int out_size, void* d_ws, size_t ws_size,
                              hipStream_t stream) {
    const float* x    = (const float*)d_in[0];
    const int* edge   = (const int*)d_in[1];   // [2,E]: src then dst
    const int* batch  = (const int*)d_in[2];
    const float* W_in = (const float*)d_in[3];
    const float* b_in = (const float*)d_in[4];
    const float* W1   = (const float*)d_in[5];
    const float* b1   = (const float*)d_in[6];
    const float* W2   = (const float*)d_in[7];
    const float* b2   = (const float*)d_in[8];
    const float* Wf1  = (const float*)d_in[9];
    const float* bf1  = (const float*)d_in[10];
    const float* Wf2  = (const float*)d_in[11];
    const float* bf2  = (const float*)d_in[12];
    float* out = (float*)d_out;

    char* ws = (char*)d_ws;
    size_t off = 0;
    auto alloc = [&](size_t bytes) -> void* {
        void* p = ws + off;
        off += (bytes + 511) & ~(size_t)511;
        return p;
    };
    // zero region: counts + pools + {goff, ticket, glo[17]} -> one memset
    int* counts   = (int*)alloc((size_t)NN * 4);
    float* pools  = (float*)alloc(16 * 128 * 4);
    int* misc     = (int*)alloc(512);
    size_t zero_bytes = off;
    int* goff     = misc;
    int* ticket   = misc + 1;
    int* glo      = misc + 8;                      // 17 ints
    ushort* bufA  = (ushort*)alloc((size_t)NN * 128 * 2);   // hw1 = x@(W_in@W1)
    ushort* bufB  = (ushort*)alloc((size_t)NN * 128 * 2);   // h2 (layer-2 out)
    ushort* bufC  = (ushort*)alloc((size_t)NN * 128 * 2);   // hw2 = h1@W2
    ushort* Bp1   = (ushort*)alloc(128 * 128 * 2);
    ushort* Bp2   = (ushort*)alloc(128 * 128 * 2);
    float* cvec   = (float*)alloc(128 * 4);
    float* dis    = (float*)alloc((size_t)NN * 4);
    uint* spack   = (uint*)alloc((size_t)NN * 4);
    int* start    = (int*)alloc((size_t)NN * 4);
    int* cursor   = (int*)alloc((size_t)NN * 4);
    uint* edata   = (uint*)alloc((size_t)EE * 4);

    hipMemsetAsync(counts, 0, zero_bytes, stream);

    histprep_kernel<<<2629, 256, 0, stream>>>(edge + EE, counts, W_in, W1, b_in, W2,
                                              batch, Bp1, Bp2, cvec, glo);
    scan_kernel<<<NCH, 256, 0, stream>>>(counts, goff, start, cursor, dis, spack, NN);
    fillmm1_kernel<<<2500 + NN / 64, 256, 0, stream>>>(edge, edge + EE, spack, cursor,
                                                       edata, x, Bp1, bufA);
    agg1m_kernel<<<NN / 16, 256, 0, stream>>>(bufA, dis, start, counts, edata,
                                              cvec, b1, Bp2, bufC);
    agg_kernel<<<NN / 4, 256, 0, stream>>>(bufC, dis, start, counts, edata, nullptr, b2, bufB, NN);
    poolfinal_kernel<<<1024, 256, 0, stream>>>(bufB, glo, pools, ticket,
                                               Wf1, bf1, Wf2, bf2, out);
}

// Round 9
// 243.882 us; speedup vs baseline: 1.2282x; 1.2282x over previous
//
#include <hip/hip_runtime.h>
#include <hip/hip_fp16.h>

#define NN 40000
#define EE 640000
#define NCH 157   // ceil(NN/256)

typedef unsigned int uint;
typedef unsigned short ushort;
typedef __attribute__((ext_vector_type(8))) short short8;
typedef __attribute__((ext_vector_type(4))) float floatx4;
typedef __attribute__((ext_vector_type(4))) uint uint4e;

// ---- bf16 helpers (RNE) ----
__device__ inline ushort f2bf(float f) {
    uint u = __float_as_uint(f);
    return (ushort)((u + 0x7fffu + ((u >> 16) & 1u)) >> 16);
}
__device__ inline float bf_lo(uint u) { return __uint_as_float(u << 16); }
__device__ inline float bf_hi(uint u) { return __uint_as_float(u & 0xffff0000u); }

__device__ inline int lower_bound_dev(const int* __restrict__ a, int n, int x) {
    int lo = 0, hi = n;
    while (lo < hi) { int m = (lo + hi) >> 1; if (a[m] < x) lo = m + 1; else hi = m; }
    return lo;
}

// ---------------- hist + weight prep + graph bounds (one launch) ----------------
__global__ __launch_bounds__(256) void histprep_kernel(const int* __restrict__ dst,
                                                       int* __restrict__ counts,
                                                       const float* __restrict__ W_in,
                                                       const float* __restrict__ W1,
                                                       const float* __restrict__ b_in,
                                                       const float* __restrict__ W2,
                                                       const int* __restrict__ batch,
                                                       ushort* __restrict__ Bp1,
                                                       ushort* __restrict__ Bp2,
                                                       float* __restrict__ cvec,
                                                       int* __restrict__ glo) {
    int b = blockIdx.x, t = threadIdx.x;
    if (b < 2500) {
        atomicAdd(&counts[dst[b * 256 + t]], 1);
    } else if (b < 2564) {
        int idx = (b - 2500) * 256 + t;
        int k = idx >> 7, n = idx & 127;
        float s = 0.f;
        for (int j = 0; j < 128; ++j) s = fmaf(W_in[k * 128 + j], W1[j * 128 + n], s);
        Bp1[((size_t)(k >> 3) * 128 + n) * 8 + (k & 7)] = f2bf(s);
    } else if (b < 2628) {
        int idx = (b - 2564) * 256 + t;
        int k = idx >> 7, n = idx & 127;
        Bp2[((size_t)(k >> 3) * 128 + n) * 8 + (k & 7)] = f2bf(W2[idx]);
    } else {
        if (t < 128) {
            float s = 0.f;
            for (int k = 0; k < 128; ++k) s = fmaf(b_in[k], W1[k * 128 + t], s);
            cvec[t] = s;
        } else if (t < 128 + 17) {
            int g = t - 128;                      // 0..16
            glo[g] = lower_bound_dev(batch, NN, g);
        }
    }
}

// ---------------- single-pass CSR offsets + spack ----------------
// spack[i] = i | fp16(dis[i])<<16 — the per-edge payload is just spack[src].
__global__ __launch_bounds__(256) void scan_kernel(const int* __restrict__ counts,
                                                   int* __restrict__ goff,
                                                   int* __restrict__ start,
                                                   int* __restrict__ cursor,
                                                   float* __restrict__ dis,
                                                   uint* __restrict__ spack, int N) {
    __shared__ int ws[4];
    __shared__ int sbase;
    int t = threadIdx.x, lane = t & 63, wv = t >> 6;
    int idx = blockIdx.x * 256 + t;
    int c = (idx < N) ? counts[idx] : 0;
    int v = c;
    #pragma unroll
    for (int d = 1; d < 64; d <<= 1) {
        int u = __shfl_up(v, d, 64);
        if (lane >= d) v += u;
    }
    if (lane == 63) ws[wv] = v;
    __syncthreads();
    if (t == 0) {
        int total = ws[0] + ws[1] + ws[2] + ws[3];
        sbase = atomicAdd(goff, total);
    }
    __syncthreads();
    int off = sbase;
    for (int j = 0; j < wv; ++j) off += ws[j];
    if (idx < N) {
        int excl = off + v - c;
        start[idx] = excl;
        cursor[idx] = excl;
        float dv = rsqrtf((float)c + 1.0f);
        dis[idx] = dv;
        spack[idx] = (uint)idx | ((uint)__half_as_ushort(__float2half_rn(dv)) << 16);
    }
}

// ---- MFMA 64-row tile: C[64,128](bf16) = A[64,128] @ Bpack (row-major C) ----
template <bool ABF16>
__device__ inline void mm_tile(const void* __restrict__ Av, const ushort* __restrict__ Bpack,
                               ushort* __restrict__ C, int tile, int wv, int lane) {
    int m = lane & 15, q = lane >> 4;
    int row = tile * 64 + wv * 16 + m;

    short8 afr[4];
    if (ABF16) {
        const ushort* A = (const ushort*)Av;
        const ushort* ap = A + (size_t)row * 128 + q * 8;
        #pragma unroll
        for (int k0 = 0; k0 < 4; ++k0) afr[k0] = *(const short8*)(ap + k0 * 32);
    } else {
        const float* A = (const float*)Av;
        const float* ap = A + (size_t)row * 128 + q * 8;
        #pragma unroll
        for (int k0 = 0; k0 < 4; ++k0) {
            float4 f0 = *(const float4*)(ap + k0 * 32);
            float4 f1 = *(const float4*)(ap + k0 * 32 + 4);
            short8 a;
            a[0] = (short)f2bf(f0.x); a[1] = (short)f2bf(f0.y);
            a[2] = (short)f2bf(f0.z); a[3] = (short)f2bf(f0.w);
            a[4] = (short)f2bf(f1.x); a[5] = (short)f2bf(f1.y);
            a[6] = (short)f2bf(f1.z); a[7] = (short)f2bf(f1.w);
            afr[k0] = a;
        }
    }

    floatx4 acc[8];
    #pragma unroll
    for (int nt = 0; nt < 8; ++nt) { floatx4 z = {0.f, 0.f, 0.f, 0.f}; acc[nt] = z; }

    #pragma unroll
    for (int nt = 0; nt < 8; ++nt) {
        #pragma unroll
        for (int k0 = 0; k0 < 4; ++k0) {
            short8 bfrag = *(const short8*)(Bpack + ((size_t)(k0 * 4 + q) * 128 + nt * 16 + m) * 8);
            acc[nt] = __builtin_amdgcn_mfma_f32_16x16x32_bf16(afr[k0], bfrag, acc[nt], 0, 0, 0);
        }
    }

    int orow_base = tile * 64 + wv * 16 + q * 4;
    #pragma unroll
    for (int nt = 0; nt < 8; ++nt) {
        #pragma unroll
        for (int r = 0; r < 4; ++r)
            C[(size_t)(orow_base + r) * 128 + nt * 16 + m] = f2bf(acc[nt][r]);
    }
}

// ---------------- fill CSR ∪ mm1 (independent, one launch) ----------------
// edata entry = spack[src]: low 16 = src id, high 16 = fp16 dis[src].
// dis[dst] is factored out of the edge loop (applied once per node in agg).
__global__ __launch_bounds__(256) void fillmm1_kernel(const int* __restrict__ src,
                                                      const int* __restrict__ dst,
                                                      const uint* __restrict__ spack,
                                                      int* __restrict__ cursor,
                                                      uint* __restrict__ edata,
                                                      const float* __restrict__ x,
                                                      const ushort* __restrict__ Bp1,
                                                      ushort* __restrict__ bufA) {
    int b = blockIdx.x, t = threadIdx.x;
    if (b < 2500) {
        int e = b * 256 + t;
        int s = src[e], d = dst[e];
        int pos = atomicAdd(&cursor[d], 1);
        edata[pos] = spack[s];
    } else {
        mm_tile<false>(x, Bp1, bufA, b - 2500, t >> 6, t & 63);
    }
}

// ---------------- layer-1: aggregation fused with @W2 (MFMA from LDS A-tile) ----
// 2500 blocks x 256 threads. Each of 4 waves gathers 4 consecutive dst nodes ->
// 16-row bf16 A-tile in LDS (16B slots, XOR swizzle slot ^= row&7, same key
// write/read). After one barrier each wave computes 2 of 8 column-tiles.
// Edge weights are fp16(dis[s]); dis[i] is applied once after the fold.
__global__ __launch_bounds__(256) void agg1m_kernel(const ushort* __restrict__ hw,
                                                    const float* __restrict__ dis,
                                                    const int* __restrict__ start,
                                                    const int* __restrict__ counts,
                                                    const uint* __restrict__ edata,
                                                    const float* __restrict__ cvec,
                                                    const float* __restrict__ bias,
                                                    const ushort* __restrict__ Bp2,
                                                    ushort* __restrict__ C) {
    __shared__ ushort Atile[16][128];   // 4 KB, swizzled 16B slots
    __shared__ uint eds[4][64];
    int t = threadIdx.x;
    int wv = t >> 6, lane = t & 63;
    int qg = lane & 15, h4 = lane >> 4;   // gather roles
    const uint4* __restrict__ hv4 = (const uint4*)hw;
    int base = blockIdx.x * 16;
    char* abase = (char*)&Atile[0][0];

    for (int n = 0; n < 4; ++n) {
        int nl = wv * 4 + n;              // local row 0..15
        int i = base + nl;
        int beg = start[i];
        int deg = counts[i];
        int dmain = deg > 64 ? 64 : deg;

        uint ed;
        if (lane < dmain) ed = edata[beg + lane];
        else ed = (uint)i;                // pad: self row, fp16 norm bits = 0
        eds[wv][lane] = ed;

        float a0 = 0.f, a1 = 0.f, a2 = 0.f, a3 = 0.f;
        float a4 = 0.f, a5 = 0.f, a6 = 0.f, a7 = 0.f;
        float sn = 0.f;

        int dpad = (dmain + 15) & ~15;
        for (int j = 0; j < dpad; j += 16) {
            uint e0 = eds[wv][j + h4];
            uint e1 = eds[wv][j + 4 + h4];
            uint e2 = eds[wv][j + 8 + h4];
            uint e3 = eds[wv][j + 12 + h4];
            uint4 u0 = hv4[(size_t)(e0 & 0xffffu) * 16 + qg];
            uint4 u1 = hv4[(size_t)(e1 & 0xffffu) * 16 + qg];
            uint4 u2 = hv4[(size_t)(e2 & 0xffffu) * 16 + qg];
            uint4 u3 = hv4[(size_t)(e3 & 0xffffu) * 16 + qg];
            float n0 = __half2float(__ushort_as_half((ushort)(e0 >> 16)));
            float n1 = __half2float(__ushort_as_half((ushort)(e1 >> 16)));
            float n2 = __half2float(__ushort_as_half((ushort)(e2 >> 16)));
            float n3 = __half2float(__ushort_as_half((ushort)(e3 >> 16)));
            a0 = fmaf(n0, bf_lo(u0.x), a0); a1 = fmaf(n0, bf_hi(u0.x), a1);
            a2 = fmaf(n0, bf_lo(u0.y), a2); a3 = fmaf(n0, bf_hi(u0.y), a3);
            a4 = fmaf(n0, bf_lo(u0.z), a4); a5 = fmaf(n0, bf_hi(u0.z), a5);
            a6 = fmaf(n0, bf_lo(u0.w), a6); a7 = fmaf(n0, bf_hi(u0.w), a7);
            a0 = fmaf(n1, bf_lo(u1.x), a0); a1 = fmaf(n1, bf_hi(u1.x), a1);
            a2 = fmaf(n1, bf_lo(u1.y), a2); a3 = fmaf(n1, bf_hi(u1.y), a3);
            a4 = fmaf(n1, bf_lo(u1.z), a4); a5 = fmaf(n1, bf_hi(u1.z), a5);
            a6 = fmaf(n1, bf_lo(u1.w), a6); a7 = fmaf(n1, bf_hi(u1.w), a7);
            a0 = fmaf(n2, bf_lo(u2.x), a0); a1 = fmaf(n2, bf_hi(u2.x), a1);
            a2 = fmaf(n2, bf_lo(u2.y), a2); a3 = fmaf(n2, bf_hi(u2.y), a3);
            a4 = fmaf(n2, bf_lo(u2.z), a4); a5 = fmaf(n2, bf_hi(u2.z), a5);
            a6 = fmaf(n2, bf_lo(u2.w), a6); a7 = fmaf(n2, bf_hi(u2.w), a7);
            a0 = fmaf(n3, bf_lo(u3.x), a0); a1 = fmaf(n3, bf_hi(u3.x), a1);
            a2 = fmaf(n3, bf_lo(u3.y), a2); a3 = fmaf(n3, bf_hi(u3.y), a3);
            a4 = fmaf(n3, bf_lo(u3.z), a4); a5 = fmaf(n3, bf_hi(u3.z), a5);
            a6 = fmaf(n3, bf_lo(u3.w), a6); a7 = fmaf(n3, bf_hi(u3.w), a7);
            sn += (n0 + n1) + (n2 + n3);
        }
        for (int e = beg + 64; e < beg + deg; ++e) {   // rare deg>64 tail
            uint et = edata[e];
            if (h4 == 0) {
                float n0 = __half2float(__ushort_as_half((ushort)(et >> 16)));
                uint4 u = hv4[(size_t)(et & 0xffffu) * 16 + qg];
                a0 = fmaf(n0, bf_lo(u.x), a0); a1 = fmaf(n0, bf_hi(u.x), a1);
                a2 = fmaf(n0, bf_lo(u.y), a2); a3 = fmaf(n0, bf_hi(u.y), a3);
                a4 = fmaf(n0, bf_lo(u.z), a4); a5 = fmaf(n0, bf_hi(u.z), a5);
                a6 = fmaf(n0, bf_lo(u.w), a6); a7 = fmaf(n0, bf_hi(u.w), a7);
                sn += n0;
            }
        }

        a0 += __shfl_xor(a0, 16); a0 += __shfl_xor(a0, 32);
        a1 += __shfl_xor(a1, 16); a1 += __shfl_xor(a1, 32);
        a2 += __shfl_xor(a2, 16); a2 += __shfl_xor(a2, 32);
        a3 += __shfl_xor(a3, 16); a3 += __shfl_xor(a3, 32);
        a4 += __shfl_xor(a4, 16); a4 += __shfl_xor(a4, 32);
        a5 += __shfl_xor(a5, 16); a5 += __shfl_xor(a5, 32);
        a6 += __shfl_xor(a6, 16); a6 += __shfl_xor(a6, 32);
        a7 += __shfl_xor(a7, 16); a7 += __shfl_xor(a7, 32);
        sn += __shfl_xor(sn, 16); sn += __shfl_xor(sn, 32);

        // apply dis[i] (factored out of edge loop), then self-loop term
        float di = dis[i];
        float sii = di * di;
        a0 *= di; a1 *= di; a2 *= di; a3 *= di;
        a4 *= di; a5 *= di; a6 *= di; a7 *= di;
        sn *= di;
        uint4 su = hv4[(size_t)i * 16 + qg];
        a0 = fmaf(sii, bf_lo(su.x), a0); a1 = fmaf(sii, bf_hi(su.x), a1);
        a2 = fmaf(sii, bf_lo(su.y), a2); a3 = fmaf(sii, bf_hi(su.y), a3);
        a4 = fmaf(sii, bf_lo(su.z), a4); a5 = fmaf(sii, bf_hi(su.z), a5);
        a6 = fmaf(sii, bf_lo(su.w), a6); a7 = fmaf(sii, bf_hi(su.w), a7);
        sn += sii;

        float4 ca = *(const float4*)(cvec + 8 * qg);
        float4 cb = *(const float4*)(cvec + 8 * qg + 4);
        float4 ba = *(const float4*)(bias + 8 * qg);
        float4 bb = *(const float4*)(bias + 8 * qg + 4);
        float o0 = fmaxf(fmaf(sn, ca.x, a0) + ba.x, 0.f);
        float o1 = fmaxf(fmaf(sn, ca.y, a1) + ba.y, 0.f);
        float o2 = fmaxf(fmaf(sn, ca.z, a2) + ba.z, 0.f);
        float o3 = fmaxf(fmaf(sn, ca.w, a3) + ba.w, 0.f);
        float o4 = fmaxf(fmaf(sn, cb.x, a4) + bb.x, 0.f);
        float o5 = fmaxf(fmaf(sn, cb.y, a5) + bb.y, 0.f);
        float o6 = fmaxf(fmaf(sn, cb.z, a6) + bb.z, 0.f);
        float o7 = fmaxf(fmaf(sn, cb.w, a7) + bb.w, 0.f);

        if (h4 == 0) {
            uint4e o;
            o.x = (uint)f2bf(o0) | ((uint)f2bf(o1) << 16);
            o.y = (uint)f2bf(o2) | ((uint)f2bf(o3) << 16);
            o.z = (uint)f2bf(o4) | ((uint)f2bf(o5) << 16);
            o.w = (uint)f2bf(o6) | ((uint)f2bf(o7) << 16);
            int slot = qg ^ (nl & 7);
            *(uint4e*)(abase + nl * 256 + slot * 16) = o;
        }
    }

    __syncthreads();

    {
        int m = lane & 15, qm = lane >> 4;
        short8 afr[4];
        #pragma unroll
        for (int k0 = 0; k0 < 4; ++k0) {
            int slot = (qm + 4 * k0) ^ (m & 7);
            afr[k0] = *(const short8*)(abase + m * 256 + slot * 16);
        }
        floatx4 acc[2];
        #pragma unroll
        for (int u = 0; u < 2; ++u) { floatx4 z = {0.f, 0.f, 0.f, 0.f}; acc[u] = z; }
        #pragma unroll
        for (int u = 0; u < 2; ++u) {
            int nt = 2 * wv + u;
            #pragma unroll
            for (int k0 = 0; k0 < 4; ++k0) {
                short8 bfrag = *(const short8*)(Bp2 + ((size_t)(k0 * 4 + qm) * 128 + nt * 16 + m) * 8);
                acc[u] = __builtin_amdgcn_mfma_f32_16x16x32_bf16(afr[k0], bfrag, acc[u], 0, 0, 0);
            }
        }
        int orow_base = base + qm * 4;
        #pragma unroll
        for (int u = 0; u < 2; ++u) {
            int nt = 2 * wv + u;
            #pragma unroll
            for (int r = 0; r < 4; ++r)
                C[(size_t)(orow_base + r) * 128 + nt * 16 + m] = f2bf(acc[u][r]);
        }
    }
}

// ---------------- GCN aggregation (layer 2): one wave per dst node ----------------
__global__ __launch_bounds__(256) void agg_kernel(const ushort* __restrict__ hw,
                                                  const float* __restrict__ dis,
                                                  const int* __restrict__ start,
                                                  const int* __restrict__ counts,
                                                  const uint* __restrict__ edata,
                                                  const float* __restrict__ cvec,
                                                  const float* __restrict__ bias,
                                                  ushort* __restrict__ out, int N) {
    __shared__ uint eds[4][64];
    int wv = threadIdx.x >> 6;
    int lane = threadIdx.x & 63;
    int q = lane & 15, h4 = lane >> 4;
    int i = blockIdx.x * 4 + wv;
    if (i >= N) return;
    int beg = start[i];
    int deg = counts[i];
    int dmain = deg > 64 ? 64 : deg;
    const uint4* __restrict__ hv4 = (const uint4*)hw;

    uint ed;
    if (lane < dmain) ed = edata[beg + lane];
    else ed = (uint)i;
    eds[wv][lane] = ed;

    float a0 = 0.f, a1 = 0.f, a2 = 0.f, a3 = 0.f;
    float a4 = 0.f, a5 = 0.f, a6 = 0.f, a7 = 0.f;
    float sn = 0.f;

    int dpad = (dmain + 15) & ~15;
    for (int j = 0; j < dpad; j += 16) {
        uint e0 = eds[wv][j + h4];
        uint e1 = eds[wv][j + 4 + h4];
        uint e2 = eds[wv][j + 8 + h4];
        uint e3 = eds[wv][j + 12 + h4];
        uint4 u0 = hv4[(size_t)(e0 & 0xffffu) * 16 + q];
        uint4 u1 = hv4[(size_t)(e1 & 0xffffu) * 16 + q];
        uint4 u2 = hv4[(size_t)(e2 & 0xffffu) * 16 + q];
        uint4 u3 = hv4[(size_t)(e3 & 0xffffu) * 16 + q];
        float n0 = __half2float(__ushort_as_half((ushort)(e0 >> 16)));
        float n1 = __half2float(__ushort_as_half((ushort)(e1 >> 16)));
        float n2 = __half2float(__ushort_as_half((ushort)(e2 >> 16)));
        float n3 = __half2float(__ushort_as_half((ushort)(e3 >> 16)));
        a0 = fmaf(n0, bf_lo(u0.x), a0); a1 = fmaf(n0, bf_hi(u0.x), a1);
        a2 = fmaf(n0, bf_lo(u0.y), a2); a3 = fmaf(n0, bf_hi(u0.y), a3);
        a4 = fmaf(n0, bf_lo(u0.z), a4); a5 = fmaf(n0, bf_hi(u0.z), a5);
        a6 = fmaf(n0, bf_lo(u0.w), a6); a7 = fmaf(n0, bf_hi(u0.w), a7);
        a0 = fmaf(n1, bf_lo(u1.x), a0); a1 = fmaf(n1, bf_hi(u1.x), a1);
        a2 = fmaf(n1, bf_lo(u1.y), a2); a3 = fmaf(n1, bf_hi(u1.y), a3);
        a4 = fmaf(n1, bf_lo(u1.z), a4); a5 = fmaf(n1, bf_hi(u1.z), a5);
        a6 = fmaf(n1, bf_lo(u1.w), a6); a7 = fmaf(n1, bf_hi(u1.w), a7);
        a0 = fmaf(n2, bf_lo(u2.x), a0); a1 = fmaf(n2, bf_hi(u2.x), a1);
        a2 = fmaf(n2, bf_lo(u2.y), a2); a3 = fmaf(n2, bf_hi(u2.y), a3);
        a4 = fmaf(n2, bf_lo(u2.z), a4); a5 = fmaf(n2, bf_hi(u2.z), a5);
        a6 = fmaf(n2, bf_lo(u2.w), a6); a7 = fmaf(n2, bf_hi(u2.w), a7);
        a0 = fmaf(n3, bf_lo(u3.x), a0); a1 = fmaf(n3, bf_hi(u3.x), a1);
        a2 = fmaf(n3, bf_lo(u3.y), a2); a3 = fmaf(n3, bf_hi(u3.y), a3);
        a4 = fmaf(n3, bf_lo(u3.z), a4); a5 = fmaf(n3, bf_hi(u3.z), a5);
        a6 = fmaf(n3, bf_lo(u3.w), a6); a7 = fmaf(n3, bf_hi(u3.w), a7);
        sn += (n0 + n1) + (n2 + n3);
    }
    for (int e = beg + 64; e < beg + deg; ++e) {
        uint et = edata[e];
        if (h4 == 0) {
            float n0 = __half2float(__ushort_as_half((ushort)(et >> 16)));
            uint4 u = hv4[(size_t)(et & 0xffffu) * 16 + q];
            a0 = fmaf(n0, bf_lo(u.x), a0); a1 = fmaf(n0, bf_hi(u.x), a1);
            a2 = fmaf(n0, bf_lo(u.y), a2); a3 = fmaf(n0, bf_hi(u.y), a3);
            a4 = fmaf(n0, bf_lo(u.z), a4); a5 = fmaf(n0, bf_hi(u.z), a5);
            a6 = fmaf(n0, bf_lo(u.w), a6); a7 = fmaf(n0, bf_hi(u.w), a7);
            sn += n0;
        }
    }

    a0 += __shfl_xor(a0, 16); a0 += __shfl_xor(a0, 32);
    a1 += __shfl_xor(a1, 16); a1 += __shfl_xor(a1, 32);
    a2 += __shfl_xor(a2, 16); a2 += __shfl_xor(a2, 32);
    a3 += __shfl_xor(a3, 16); a3 += __shfl_xor(a3, 32);
    a4 += __shfl_xor(a4, 16); a4 += __shfl_xor(a4, 32);
    a5 += __shfl_xor(a5, 16); a5 += __shfl_xor(a5, 32);
    a6 += __shfl_xor(a6, 16); a6 += __shfl_xor(a6, 32);
    a7 += __shfl_xor(a7, 16); a7 += __shfl_xor(a7, 32);
    sn += __shfl_xor(sn, 16); sn += __shfl_xor(sn, 32);

    // apply dis[i] (factored out of edge loop), then self-loop term
    float di = dis[i];
    float sii = di * di;
    a0 *= di; a1 *= di; a2 *= di; a3 *= di;
    a4 *= di; a5 *= di; a6 *= di; a7 *= di;
    sn *= di;
    uint4 su = hv4[(size_t)i * 16 + q];
    a0 = fmaf(sii, bf_lo(su.x), a0); a1 = fmaf(sii, bf_hi(su.x), a1);
    a2 = fmaf(sii, bf_lo(su.y), a2); a3 = fmaf(sii, bf_hi(su.y), a3);
    a4 = fmaf(sii, bf_lo(su.z), a4); a5 = fmaf(sii, bf_hi(su.z), a5);
    a6 = fmaf(sii, bf_lo(su.w), a6); a7 = fmaf(sii, bf_hi(su.w), a7);
    sn += sii;

    float c0 = 0.f, c1 = 0.f, c2 = 0.f, c3 = 0.f;
    float c4 = 0.f, c5 = 0.f, c6 = 0.f, c7 = 0.f;
    if (cvec) {
        float4 ca = *(const float4*)(cvec + 8 * q);
        float4 cb = *(const float4*)(cvec + 8 * q + 4);
        c0 = ca.x; c1 = ca.y; c2 = ca.z; c3 = ca.w;
        c4 = cb.x; c5 = cb.y; c6 = cb.z; c7 = cb.w;
    }
    float4 ba = *(const float4*)(bias + 8 * q);
    float4 bb = *(const float4*)(bias + 8 * q + 4);
    float o0 = fmaxf(fmaf(sn, c0, a0) + ba.x, 0.f);
    float o1 = fmaxf(fmaf(sn, c1, a1) + ba.y, 0.f);
    float o2 = fmaxf(fmaf(sn, c2, a2) + ba.z, 0.f);
    float o3 = fmaxf(fmaf(sn, c3, a3) + ba.w, 0.f);
    float o4 = fmaxf(fmaf(sn, c4, a4) + bb.x, 0.f);
    float o5 = fmaxf(fmaf(sn, c5, a5) + bb.y, 0.f);
    float o6 = fmaxf(fmaf(sn, c6, a6) + bb.z, 0.f);
    float o7 = fmaxf(fmaf(sn, c7, a7) + bb.w, 0.f);
    if (h4 == 0) {
        uint4 o;
        o.x = (uint)f2bf(o0) | ((uint)f2bf(o1) << 16);
        o.y = (uint)f2bf(o2) | ((uint)f2bf(o3) << 16);
        o.z = (uint)f2bf(o4) | ((uint)f2bf(o5) << 16);
        o.w = (uint)f2bf(o6) | ((uint)f2bf(o7) << 16);
        ((uint4*)out)[(size_t)i * 16 + q] = o;
    }
}

// ---------------- pool: per-(graph,chunk) partial sums, no fence/ticket ----------
// 1024 blocks (64 chunks/graph). Kernel boundary orders pools for final_kernel.
__global__ __launch_bounds__(256) void pool_kernel(const ushort* __restrict__ h,
                                                   const int* __restrict__ glo,
                                                   float* __restrict__ pools) {
    int t = threadIdx.x, c2 = t & 63, wv = t >> 6;
    int b = blockIdx.x;
    int g = b >> 6, ch = b & 63;
    int lo = glo[g], hi = glo[g + 1];
    int span = hi - lo;
    int chunk = (span + 63) >> 6;
    int r0 = lo + ch * chunk;
    int r1 = hi < r0 + chunk ? hi : r0 + chunk;
    const uint* __restrict__ hv = (const uint*)h;

    float a0 = 0.f, a1 = 0.f;
    #pragma unroll 4
    for (int j = r0 + wv; j < r1; j += 4) {
        uint u = hv[(size_t)j * 64 + c2];
        a0 += bf_lo(u);
        a1 += bf_hi(u);
    }
    if (r0 < r1) {
        atomicAdd(&pools[g * 128 + 2 * c2], a0);
        atomicAdd(&pools[g * 128 + 2 * c2 + 1], a1);
    }
}

// ---------------- final MLP head: one block ----------------
__global__ __launch_bounds__(256) void final_kernel(const int* __restrict__ glo,
                                                    const float* __restrict__ pools,
                                                    const float* __restrict__ Wf1,
                                                    const float* __restrict__ bf1,
                                                    const float* __restrict__ Wf2,
                                                    const float* __restrict__ bf2,
                                                    float* __restrict__ out) {
    __shared__ float pooled[16][128];
    __shared__ float z[16][64];
    int t = threadIdx.x;
    for (int idx = t; idx < 2048; idx += 256) {
        int gg = idx >> 7, c = idx & 127;
        int cn = glo[gg + 1] - glo[gg];
        float cnf = (float)(cn > 1 ? cn : 1);
        pooled[gg][c] = pools[idx] / cnf;
    }
    __syncthreads();
    for (int idx = t; idx < 1024; idx += 256) {
        int gg = idx >> 6, j = idx & 63;
        float s = bf1[j];
        for (int k = 0; k < 128; ++k) s = fmaf(pooled[gg][k], Wf1[k * 64 + j], s);
        z[gg][j] = fmaxf(s, 0.f);
    }
    __syncthreads();
    if (t < 160) {
        int gg = t / 10, k = t % 10;
        float s = bf2[k];
        for (int j = 0; j < 64; ++j) s = fmaf(z[gg][j], Wf2[j * 10 + k], s);
        out[t] = s;
    }
}

// ---------------- launch ----------------

extern "C" void kernel_launch(void* const* d_in, const int* in_sizes, int n_in,
                              void* d_out, int out_size, void* d_ws, size_t ws_size,
                              hipStream_t stream) {
    const float* x    = (const float*)d_in[0];
    const int* edge   = (const int*)d_in[1];   // [2,E]: src then dst
    const int* batch  = (const int*)d_in[2];
    const float* W_in = (const float*)d_in[3];
    const float* b_in = (const float*)d_in[4];
    const float* W1   = (const float*)d_in[5];
    const float* b1   = (const float*)d_in[6];
    const float* W2   = (const float*)d_in[7];
    const float* b2   = (const float*)d_in[8];
    const float* Wf1  = (const float*)d_in[9];
    const float* bf1  = (const float*)d_in[10];
    const float* Wf2  = (const float*)d_in[11];
    const float* bf2  = (const float*)d_in[12];
    float* out = (float*)d_out;

    char* ws = (char*)d_ws;
    size_t off = 0;
    auto alloc = [&](size_t bytes) -> void* {
        void* p = ws + off;
        off += (bytes + 511) & ~(size_t)511;
        return p;
    };
    // zero region: counts + pools + {goff, glo[17]} -> one memset
    int* counts   = (int*)alloc((size_t)NN * 4);
    float* pools  = (float*)alloc(16 * 128 * 4);
    int* misc     = (int*)alloc(512);
    size_t zero_bytes = off;
    int* goff     = misc;
    int* glo      = misc + 8;                      // 17 ints
    ushort* bufA  = (ushort*)alloc((size_t)NN * 128 * 2);   // hw1 = x@(W_in@W1)
    ushort* bufB  = (ushort*)alloc((size_t)NN * 128 * 2);   // h2 (layer-2 out)
    ushort* bufC  = (ushort*)alloc((size_t)NN * 128 * 2);   // hw2 = h1@W2
    ushort* Bp1   = (ushort*)alloc(128 * 128 * 2);
    ushort* Bp2   = (ushort*)alloc(128 * 128 * 2);
    float* cvec   = (float*)alloc(128 * 4);
    float* dis    = (float*)alloc((size_t)NN * 4);
    uint* spack   = (uint*)alloc((size_t)NN * 4);
    int* start    = (int*)alloc((size_t)NN * 4);
    int* cursor   = (int*)alloc((size_t)NN * 4);
    uint* edata   = (uint*)alloc((size_t)EE * 4);

    hipMemsetAsync(counts, 0, zero_bytes, stream);

    histprep_kernel<<<2629, 256, 0, stream>>>(edge + EE, counts, W_in, W1, b_in, W2,
                                              batch, Bp1, Bp2, cvec, glo);
    scan_kernel<<<NCH, 256, 0, stream>>>(counts, goff, start, cursor, dis, spack, NN);
    fillmm1_kernel<<<2500 + NN / 64, 256, 0, stream>>>(edge, edge + EE, spack, cursor,
                                                       edata, x, Bp1, bufA);
    agg1m_kernel<<<NN / 16, 256, 0, stream>>>(bufA, dis, start, counts, edata,
                                              cvec, b1, Bp2, bufC);
    agg_kernel<<<NN / 4, 256, 0, stream>>>(bufC, dis, start, counts, edata, nullptr, b2, bufB, NN);
    pool_kernel<<<1024, 256, 0, stream>>>(bufB, glo, pools);
    final_kernel<<<1, 256, 0, stream>>>(glo, pools, Wf1, bf1, Wf2, bf2, out);
}

// Round 10
// 221.733 us; speedup vs baseline: 1.3508x; 1.0999x over previous
//
#include <hip/hip_runtime.h>
#include <hip/hip_fp16.h>

#define NN 40000
#define EE 640000
#define NCH 157   // ceil(NN/256)

typedef unsigned int uint;
typedef unsigned short ushort;
typedef __attribute__((ext_vector_type(8))) short short8;
typedef __attribute__((ext_vector_type(4))) float floatx4;
typedef __attribute__((ext_vector_type(4))) uint uint4e;

// ---- bf16 helpers (RNE) ----
__device__ inline ushort f2bf(float f) {
    uint u = __float_as_uint(f);
    return (ushort)((u + 0x7fffu + ((u >> 16) & 1u)) >> 16);
}
__device__ inline float bf_lo(uint u) { return __uint_as_float(u << 16); }
__device__ inline float bf_hi(uint u) { return __uint_as_float(u & 0xffff0000u); }

__device__ inline int lower_bound_dev(const int* __restrict__ a, int n, int x) {
    int lo = 0, hi = n;
    while (lo < hi) { int m = (lo + hi) >> 1; if (a[m] < x) lo = m + 1; else hi = m; }
    return lo;
}

// ---------------- weight prep + graph bounds (129 blocks, no 640K hist) ----------
__global__ __launch_bounds__(256) void prep_kernel(const float* __restrict__ W_in,
                                                   const float* __restrict__ W1,
                                                   const float* __restrict__ b_in,
                                                   const float* __restrict__ W2,
                                                   const int* __restrict__ batch,
                                                   ushort* __restrict__ Bp1,
                                                   ushort* __restrict__ Bp2,
                                                   float* __restrict__ cvec,
                                                   int* __restrict__ glo) {
    int b = blockIdx.x, t = threadIdx.x;
    if (b < 64) {
        int idx = b * 256 + t;
        int k = idx >> 7, n = idx & 127;
        float s = 0.f;
        for (int j = 0; j < 128; ++j) s = fmaf(W_in[k * 128 + j], W1[j * 128 + n], s);
        Bp1[((size_t)(k >> 3) * 128 + n) * 8 + (k & 7)] = f2bf(s);
    } else if (b < 128) {
        int idx = (b - 64) * 256 + t;
        int k = idx >> 7, n = idx & 127;
        Bp2[((size_t)(k >> 3) * 128 + n) * 8 + (k & 7)] = f2bf(W2[idx]);
    } else {
        if (t < 128) {
            float s = 0.f;
            for (int k = 0; k < 128; ++k) s = fmaf(b_in[k], W1[k * 128 + t], s);
            cvec[t] = s;
        } else if (t < 128 + 17) {
            int g = t - 128;                      // 0..16
            glo[g] = lower_bound_dev(batch, NN, g);
        }
    }
}

// ---- MFMA 64-row tile: C[64,128](bf16) = A[64,128] @ Bpack (row-major C) ----
template <bool ABF16>
__device__ inline void mm_tile(const void* __restrict__ Av, const ushort* __restrict__ Bpack,
                               ushort* __restrict__ C, int tile, int wv, int lane) {
    int m = lane & 15, q = lane >> 4;
    int row = tile * 64 + wv * 16 + m;

    short8 afr[4];
    if (ABF16) {
        const ushort* A = (const ushort*)Av;
        const ushort* ap = A + (size_t)row * 128 + q * 8;
        #pragma unroll
        for (int k0 = 0; k0 < 4; ++k0) afr[k0] = *(const short8*)(ap + k0 * 32);
    } else {
        const float* A = (const float*)Av;
        const float* ap = A + (size_t)row * 128 + q * 8;
        #pragma unroll
        for (int k0 = 0; k0 < 4; ++k0) {
            float4 f0 = *(const float4*)(ap + k0 * 32);
            float4 f1 = *(const float4*)(ap + k0 * 32 + 4);
            short8 a;
            a[0] = (short)f2bf(f0.x); a[1] = (short)f2bf(f0.y);
            a[2] = (short)f2bf(f0.z); a[3] = (short)f2bf(f0.w);
            a[4] = (short)f2bf(f1.x); a[5] = (short)f2bf(f1.y);
            a[6] = (short)f2bf(f1.z); a[7] = (short)f2bf(f1.w);
            afr[k0] = a;
        }
    }

    floatx4 acc[8];
    #pragma unroll
    for (int nt = 0; nt < 8; ++nt) { floatx4 z = {0.f, 0.f, 0.f, 0.f}; acc[nt] = z; }

    #pragma unroll
    for (int nt = 0; nt < 8; ++nt) {
        #pragma unroll
        for (int k0 = 0; k0 < 4; ++k0) {
            short8 bfrag = *(const short8*)(Bpack + ((size_t)(k0 * 4 + q) * 128 + nt * 16 + m) * 8);
            acc[nt] = __builtin_amdgcn_mfma_f32_16x16x32_bf16(afr[k0], bfrag, acc[nt], 0, 0, 0);
        }
    }

    int orow_base = tile * 64 + wv * 16 + q * 4;
    #pragma unroll
    for (int nt = 0; nt < 8; ++nt) {
        #pragma unroll
        for (int r = 0; r < 4; ++r)
            C[(size_t)(orow_base + r) * 128 + nt * 16 + m] = f2bf(acc[nt][r]);
    }
}

// ---------------- bucket fill ∪ mm1 (one launch) ----------------
// Fixed-capacity CSR: bucket[d][64] of src ids (ushort). cnt[d] counts ALL
// edges (degree). pos>=64 edges go to the overflow list (d | s<<16).
// No histogram pass, no prefix scan.
__global__ __launch_bounds__(256) void fill_kernel(const int* __restrict__ src,
                                                   const int* __restrict__ dst,
                                                   int* __restrict__ cnt,
                                                   int* __restrict__ ovfcnt,
                                                   uint* __restrict__ ovf,
                                                   ushort* __restrict__ bucket,
                                                   const float* __restrict__ x,
                                                   const ushort* __restrict__ Bp1,
                                                   ushort* __restrict__ bufA) {
    int b = blockIdx.x, t = threadIdx.x;
    if (b < 2500) {
        int e = b * 256 + t;
        int s = src[e], d = dst[e];
        int pos = atomicAdd(&cnt[d], 1);
        if (pos < 64) {
            bucket[(size_t)d * 64 + pos] = (ushort)s;
        } else {
            int k = atomicAdd(ovfcnt, 1);
            ovf[k] = (uint)d | ((uint)s << 16);
        }
    } else {
        mm_tile<false>(x, Bp1, bufA, b - 2500, t >> 6, t & 63);
    }
}

// ---------------- dis + spack (elementwise, after fill) ----------------
// spack[i] = i | fp16(dis[i])<<16
__global__ __launch_bounds__(256) void dsprep_kernel(const int* __restrict__ cnt,
                                                     float* __restrict__ dis,
                                                     uint* __restrict__ spack, int N) {
    int i = blockIdx.x * 256 + threadIdx.x;
    if (i < N) {
        float dv = rsqrtf((float)cnt[i] + 1.0f);
        dis[i] = dv;
        spack[i] = (uint)i | ((uint)__half_as_ushort(__float2half_rn(dv)) << 16);
    }
}

// ---------------- layer-1: aggregation fused with @W2 (MFMA from LDS A-tile) ----
// 2500 blocks x 256 threads; 4 waves x 4 nodes -> 16-row bf16 A-tile in LDS
// (16B slots, XOR swizzle slot ^= row&7). Staging: s = bucket[i][lane],
// ed = spack[s] (low16 s, high16 fp16 dis[s]); pad ed = i (norm 0).
// dis[i] applied once after the fold. deg>64 handled via overflow list.
__global__ __launch_bounds__(256) void agg1m_kernel(const ushort* __restrict__ hw,
                                                    const float* __restrict__ dis,
                                                    const int* __restrict__ cnt,
                                                    const ushort* __restrict__ bucket,
                                                    const uint* __restrict__ spack,
                                                    const uint* __restrict__ ovf,
                                                    const int* __restrict__ ovfcnt,
                                                    const float* __restrict__ cvec,
                                                    const float* __restrict__ bias,
                                                    const ushort* __restrict__ Bp2,
                                                    ushort* __restrict__ C) {
    __shared__ ushort Atile[16][128];   // 4 KB, swizzled 16B slots
    __shared__ uint eds[4][64];
    int t = threadIdx.x;
    int wv = t >> 6, lane = t & 63;
    int qg = lane & 15, h4 = lane >> 4;   // gather roles
    const uint4* __restrict__ hv4 = (const uint4*)hw;
    int base = blockIdx.x * 16;
    char* abase = (char*)&Atile[0][0];

    for (int n = 0; n < 4; ++n) {
        int nl = wv * 4 + n;              // local row 0..15
        int i = base + nl;
        int deg = cnt[i];
        int dmain = deg > 64 ? 64 : deg;

        uint ed = (uint)i;                // pad: self row, fp16 norm bits = 0
        if (lane < dmain) ed = spack[bucket[(size_t)i * 64 + lane]];
        eds[wv][lane] = ed;

        float a0 = 0.f, a1 = 0.f, a2 = 0.f, a3 = 0.f;
        float a4 = 0.f, a5 = 0.f, a6 = 0.f, a7 = 0.f;
        float sn = 0.f;

        int dpad = (dmain + 15) & ~15;
        for (int j = 0; j < dpad; j += 16) {
            uint e0 = eds[wv][j + h4];
            uint e1 = eds[wv][j + 4 + h4];
            uint e2 = eds[wv][j + 8 + h4];
            uint e3 = eds[wv][j + 12 + h4];
            uint4 u0 = hv4[(size_t)(e0 & 0xffffu) * 16 + qg];
            uint4 u1 = hv4[(size_t)(e1 & 0xffffu) * 16 + qg];
            uint4 u2 = hv4[(size_t)(e2 & 0xffffu) * 16 + qg];
            uint4 u3 = hv4[(size_t)(e3 & 0xffffu) * 16 + qg];
            float n0 = __half2float(__ushort_as_half((ushort)(e0 >> 16)));
            float n1 = __half2float(__ushort_as_half((ushort)(e1 >> 16)));
            float n2 = __half2float(__ushort_as_half((ushort)(e2 >> 16)));
            float n3 = __half2float(__ushort_as_half((ushort)(e3 >> 16)));
            a0 = fmaf(n0, bf_lo(u0.x), a0); a1 = fmaf(n0, bf_hi(u0.x), a1);
            a2 = fmaf(n0, bf_lo(u0.y), a2); a3 = fmaf(n0, bf_hi(u0.y), a3);
            a4 = fmaf(n0, bf_lo(u0.z), a4); a5 = fmaf(n0, bf_hi(u0.z), a5);
            a6 = fmaf(n0, bf_lo(u0.w), a6); a7 = fmaf(n0, bf_hi(u0.w), a7);
            a0 = fmaf(n1, bf_lo(u1.x), a0); a1 = fmaf(n1, bf_hi(u1.x), a1);
            a2 = fmaf(n1, bf_lo(u1.y), a2); a3 = fmaf(n1, bf_hi(u1.y), a3);
            a4 = fmaf(n1, bf_lo(u1.z), a4); a5 = fmaf(n1, bf_hi(u1.z), a5);
            a6 = fmaf(n1, bf_lo(u1.w), a6); a7 = fmaf(n1, bf_hi(u1.w), a7);
            a0 = fmaf(n2, bf_lo(u2.x), a0); a1 = fmaf(n2, bf_hi(u2.x), a1);
            a2 = fmaf(n2, bf_lo(u2.y), a2); a3 = fmaf(n2, bf_hi(u2.y), a3);
            a4 = fmaf(n2, bf_lo(u2.z), a4); a5 = fmaf(n2, bf_hi(u2.z), a5);
            a6 = fmaf(n2, bf_lo(u2.w), a6); a7 = fmaf(n2, bf_hi(u2.w), a7);
            a0 = fmaf(n3, bf_lo(u3.x), a0); a1 = fmaf(n3, bf_hi(u3.x), a1);
            a2 = fmaf(n3, bf_lo(u3.y), a2); a3 = fmaf(n3, bf_hi(u3.y), a3);
            a4 = fmaf(n3, bf_lo(u3.z), a4); a5 = fmaf(n3, bf_hi(u3.z), a5);
            a6 = fmaf(n3, bf_lo(u3.w), a6); a7 = fmaf(n3, bf_hi(u3.w), a7);
            sn += (n0 + n1) + (n2 + n3);
        }
        if (deg > 64) {                    // overflow tail (wave-uniform, ~never)
            int ovfn = *ovfcnt;
            for (int k = 0; k < ovfn; ++k) {
                uint oe = ovf[k];
                if ((int)(oe & 0xffffu) == i && h4 == 0) {
                    int s2 = (int)(oe >> 16);
                    uint sp = spack[s2];
                    float n0 = __half2float(__ushort_as_half((ushort)(sp >> 16)));
                    uint4 u = hv4[(size_t)s2 * 16 + qg];
                    a0 = fmaf(n0, bf_lo(u.x), a0); a1 = fmaf(n0, bf_hi(u.x), a1);
                    a2 = fmaf(n0, bf_lo(u.y), a2); a3 = fmaf(n0, bf_hi(u.y), a3);
                    a4 = fmaf(n0, bf_lo(u.z), a4); a5 = fmaf(n0, bf_hi(u.z), a5);
                    a6 = fmaf(n0, bf_lo(u.w), a6); a7 = fmaf(n0, bf_hi(u.w), a7);
                    sn += n0;
                }
            }
        }

        a0 += __shfl_xor(a0, 16); a0 += __shfl_xor(a0, 32);
        a1 += __shfl_xor(a1, 16); a1 += __shfl_xor(a1, 32);
        a2 += __shfl_xor(a2, 16); a2 += __shfl_xor(a2, 32);
        a3 += __shfl_xor(a3, 16); a3 += __shfl_xor(a3, 32);
        a4 += __shfl_xor(a4, 16); a4 += __shfl_xor(a4, 32);
        a5 += __shfl_xor(a5, 16); a5 += __shfl_xor(a5, 32);
        a6 += __shfl_xor(a6, 16); a6 += __shfl_xor(a6, 32);
        a7 += __shfl_xor(a7, 16); a7 += __shfl_xor(a7, 32);
        sn += __shfl_xor(sn, 16); sn += __shfl_xor(sn, 32);

        // apply dis[i] (factored out of edge loop), then self-loop term
        float di = dis[i];
        float sii = di * di;
        a0 *= di; a1 *= di; a2 *= di; a3 *= di;
        a4 *= di; a5 *= di; a6 *= di; a7 *= di;
        sn *= di;
        uint4 su = hv4[(size_t)i * 16 + qg];
        a0 = fmaf(sii, bf_lo(su.x), a0); a1 = fmaf(sii, bf_hi(su.x), a1);
        a2 = fmaf(sii, bf_lo(su.y), a2); a3 = fmaf(sii, bf_hi(su.y), a3);
        a4 = fmaf(sii, bf_lo(su.z), a4); a5 = fmaf(sii, bf_hi(su.z), a5);
        a6 = fmaf(sii, bf_lo(su.w), a6); a7 = fmaf(sii, bf_hi(su.w), a7);
        sn += sii;

        float4 ca = *(const float4*)(cvec + 8 * qg);
        float4 cb = *(const float4*)(cvec + 8 * qg + 4);
        float4 ba = *(const float4*)(bias + 8 * qg);
        float4 bb = *(const float4*)(bias + 8 * qg + 4);
        float o0 = fmaxf(fmaf(sn, ca.x, a0) + ba.x, 0.f);
        float o1 = fmaxf(fmaf(sn, ca.y, a1) + ba.y, 0.f);
        float o2 = fmaxf(fmaf(sn, ca.z, a2) + ba.z, 0.f);
        float o3 = fmaxf(fmaf(sn, ca.w, a3) + ba.w, 0.f);
        float o4 = fmaxf(fmaf(sn, cb.x, a4) + bb.x, 0.f);
        float o5 = fmaxf(fmaf(sn, cb.y, a5) + bb.y, 0.f);
        float o6 = fmaxf(fmaf(sn, cb.z, a6) + bb.z, 0.f);
        float o7 = fmaxf(fmaf(sn, cb.w, a7) + bb.w, 0.f);

        if (h4 == 0) {
            uint4e o;
            o.x = (uint)f2bf(o0) | ((uint)f2bf(o1) << 16);
            o.y = (uint)f2bf(o2) | ((uint)f2bf(o3) << 16);
            o.z = (uint)f2bf(o4) | ((uint)f2bf(o5) << 16);
            o.w = (uint)f2bf(o6) | ((uint)f2bf(o7) << 16);
            int slot = qg ^ (nl & 7);
            *(uint4e*)(abase + nl * 256 + slot * 16) = o;
        }
    }

    __syncthreads();

    {
        int m = lane & 15, qm = lane >> 4;
        short8 afr[4];
        #pragma unroll
        for (int k0 = 0; k0 < 4; ++k0) {
            int slot = (qm + 4 * k0) ^ (m & 7);
            afr[k0] = *(const short8*)(abase + m * 256 + slot * 16);
        }
        floatx4 acc[2];
        #pragma unroll
        for (int u = 0; u < 2; ++u) { floatx4 z = {0.f, 0.f, 0.f, 0.f}; acc[u] = z; }
        #pragma unroll
        for (int u = 0; u < 2; ++u) {
            int nt = 2 * wv + u;
            #pragma unroll
            for (int k0 = 0; k0 < 4; ++k0) {
                short8 bfrag = *(const short8*)(Bp2 + ((size_t)(k0 * 4 + qm) * 128 + nt * 16 + m) * 8);
                acc[u] = __builtin_amdgcn_mfma_f32_16x16x32_bf16(afr[k0], bfrag, acc[u], 0, 0, 0);
            }
        }
        int orow_base = base + qm * 4;
        #pragma unroll
        for (int u = 0; u < 2; ++u) {
            int nt = 2 * wv + u;
            #pragma unroll
            for (int r = 0; r < 4; ++r)
                C[(size_t)(orow_base + r) * 128 + nt * 16 + m] = f2bf(acc[u][r]);
        }
    }
}

// ---------------- GCN aggregation (layer 2): one wave per dst node ----------------
__global__ __launch_bounds__(256) void agg_kernel(const ushort* __restrict__ hw,
                                                  const float* __restrict__ dis,
                                                  const int* __restrict__ cnt,
                                                  const ushort* __restrict__ bucket,
                                                  const uint* __restrict__ spack,
                                                  const uint* __restrict__ ovf,
                                                  const int* __restrict__ ovfcnt,
                                                  const float* __restrict__ cvec,
                                                  const float* __restrict__ bias,
                                                  ushort* __restrict__ out, int N) {
    __shared__ uint eds[4][64];
    int wv = threadIdx.x >> 6;
    int lane = threadIdx.x & 63;
    int q = lane & 15, h4 = lane >> 4;
    int i = blockIdx.x * 4 + wv;
    if (i >= N) return;
    int deg = cnt[i];
    int dmain = deg > 64 ? 64 : deg;
    const uint4* __restrict__ hv4 = (const uint4*)hw;

    uint ed = (uint)i;
    if (lane < dmain) ed = spack[bucket[(size_t)i * 64 + lane]];
    eds[wv][lane] = ed;

    float a0 = 0.f, a1 = 0.f, a2 = 0.f, a3 = 0.f;
    float a4 = 0.f, a5 = 0.f, a6 = 0.f, a7 = 0.f;
    float sn = 0.f;

    int dpad = (dmain + 15) & ~15;
    for (int j = 0; j < dpad; j += 16) {
        uint e0 = eds[wv][j + h4];
        uint e1 = eds[wv][j + 4 + h4];
        uint e2 = eds[wv][j + 8 + h4];
        uint e3 = eds[wv][j + 12 + h4];
        uint4 u0 = hv4[(size_t)(e0 & 0xffffu) * 16 + q];
        uint4 u1 = hv4[(size_t)(e1 & 0xffffu) * 16 + q];
        uint4 u2 = hv4[(size_t)(e2 & 0xffffu) * 16 + q];
        uint4 u3 = hv4[(size_t)(e3 & 0xffffu) * 16 + q];
        float n0 = __half2float(__ushort_as_half((ushort)(e0 >> 16)));
        float n1 = __half2float(__ushort_as_half((ushort)(e1 >> 16)));
        float n2 = __half2float(__ushort_as_half((ushort)(e2 >> 16)));
        float n3 = __half2float(__ushort_as_half((ushort)(e3 >> 16)));
        a0 = fmaf(n0, bf_lo(u0.x), a0); a1 = fmaf(n0, bf_hi(u0.x), a1);
        a2 = fmaf(n0, bf_lo(u0.y), a2); a3 = fmaf(n0, bf_hi(u0.y), a3);
        a4 = fmaf(n0, bf_lo(u0.z), a4); a5 = fmaf(n0, bf_hi(u0.z), a5);
        a6 = fmaf(n0, bf_lo(u0.w), a6); a7 = fmaf(n0, bf_hi(u0.w), a7);
        a0 = fmaf(n1, bf_lo(u1.x), a0); a1 = fmaf(n1, bf_hi(u1.x), a1);
        a2 = fmaf(n1, bf_lo(u1.y), a2); a3 = fmaf(n1, bf_hi(u1.y), a3);
        a4 = fmaf(n1, bf_lo(u1.z), a4); a5 = fmaf(n1, bf_hi(u1.z), a5);
        a6 = fmaf(n1, bf_lo(u1.w), a6); a7 = fmaf(n1, bf_hi(u1.w), a7);
        a0 = fmaf(n2, bf_lo(u2.x), a0); a1 = fmaf(n2, bf_hi(u2.x), a1);
        a2 = fmaf(n2, bf_lo(u2.y), a2); a3 = fmaf(n2, bf_hi(u2.y), a3);
        a4 = fmaf(n2, bf_lo(u2.z), a4); a5 = fmaf(n2, bf_hi(u2.z), a5);
        a6 = fmaf(n2, bf_lo(u2.w), a6); a7 = fmaf(n2, bf_hi(u2.w), a7);
        a0 = fmaf(n3, bf_lo(u3.x), a0); a1 = fmaf(n3, bf_hi(u3.x), a1);
        a2 = fmaf(n3, bf_lo(u3.y), a2); a3 = fmaf(n3, bf_hi(u3.y), a3);
        a4 = fmaf(n3, bf_lo(u3.z), a4); a5 = fmaf(n3, bf_hi(u3.z), a5);
        a6 = fmaf(n3, bf_lo(u3.w), a6); a7 = fmaf(n3, bf_hi(u3.w), a7);
        sn += (n0 + n1) + (n2 + n3);
    }
    if (deg > 64) {                        // overflow tail (wave-uniform, ~never)
        int ovfn = *ovfcnt;
        for (int k = 0; k < ovfn; ++k) {
            uint oe = ovf[k];
            if ((int)(oe & 0xffffu) == i && h4 == 0) {
                int s2 = (int)(oe >> 16);
                uint sp = spack[s2];
                float n0 = __half2float(__ushort_as_half((ushort)(sp >> 16)));
                uint4 u = hv4[(size_t)s2 * 16 + q];
                a0 = fmaf(n0, bf_lo(u.x), a0); a1 = fmaf(n0, bf_hi(u.x), a1);
                a2 = fmaf(n0, bf_lo(u.y), a2); a3 = fmaf(n0, bf_hi(u.y), a3);
                a4 = fmaf(n0, bf_lo(u.z), a4); a5 = fmaf(n0, bf_hi(u.z), a5);
                a6 = fmaf(n0, bf_lo(u.w), a6); a7 = fmaf(n0, bf_hi(u.w), a7);
                sn += n0;
            }
        }
    }

    a0 += __shfl_xor(a0, 16); a0 += __shfl_xor(a0, 32);
    a1 += __shfl_xor(a1, 16); a1 += __shfl_xor(a1, 32);
    a2 += __shfl_xor(a2, 16); a2 += __shfl_xor(a2, 32);
    a3 += __shfl_xor(a3, 16); a3 += __shfl_xor(a3, 32);
    a4 += __shfl_xor(a4, 16); a4 += __shfl_xor(a4, 32);
    a5 += __shfl_xor(a5, 16); a5 += __shfl_xor(a5, 32);
    a6 += __shfl_xor(a6, 16); a6 += __shfl_xor(a6, 32);
    a7 += __shfl_xor(a7, 16); a7 += __shfl_xor(a7, 32);
    sn += __shfl_xor(sn, 16); sn += __shfl_xor(sn, 32);

    // apply dis[i] (factored out of edge loop), then self-loop term
    float di = dis[i];
    float sii = di * di;
    a0 *= di; a1 *= di; a2 *= di; a3 *= di;
    a4 *= di; a5 *= di; a6 *= di; a7 *= di;
    sn *= di;
    uint4 su = hv4[(size_t)i * 16 + q];
    a0 = fmaf(sii, bf_lo(su.x), a0); a1 = fmaf(sii, bf_hi(su.x), a1);
    a2 = fmaf(sii, bf_lo(su.y), a2); a3 = fmaf(sii, bf_hi(su.y), a3);
    a4 = fmaf(sii, bf_lo(su.z), a4); a5 = fmaf(sii, bf_hi(su.z), a5);
    a6 = fmaf(sii, bf_lo(su.w), a6); a7 = fmaf(sii, bf_hi(su.w), a7);
    sn += sii;

    float c0 = 0.f, c1 = 0.f, c2 = 0.f, c3 = 0.f;
    float c4 = 0.f, c5 = 0.f, c6 = 0.f, c7 = 0.f;
    if (cvec) {
        float4 ca = *(const float4*)(cvec + 8 * q);
        float4 cb = *(const float4*)(cvec + 8 * q + 4);
        c0 = ca.x; c1 = ca.y; c2 = ca.z; c3 = ca.w;
        c4 = cb.x; c5 = cb.y; c6 = cb.z; c7 = cb.w;
    }
    float4 ba = *(const float4*)(bias + 8 * q);
    float4 bb = *(const float4*)(bias + 8 * q + 4);
    float o0 = fmaxf(fmaf(sn, c0, a0) + ba.x, 0.f);
    float o1 = fmaxf(fmaf(sn, c1, a1) + ba.y, 0.f);
    float o2 = fmaxf(fmaf(sn, c2, a2) + ba.z, 0.f);
    float o3 = fmaxf(fmaf(sn, c3, a3) + ba.w, 0.f);
    float o4 = fmaxf(fmaf(sn, c4, a4) + bb.x, 0.f);
    float o5 = fmaxf(fmaf(sn, c5, a5) + bb.y, 0.f);
    float o6 = fmaxf(fmaf(sn, c6, a6) + bb.z, 0.f);
    float o7 = fmaxf(fmaf(sn, c7, a7) + bb.w, 0.f);
    if (h4 == 0) {
        uint4 o;
        o.x = (uint)f2bf(o0) | ((uint)f2bf(o1) << 16);
        o.y = (uint)f2bf(o2) | ((uint)f2bf(o3) << 16);
        o.z = (uint)f2bf(o4) | ((uint)f2bf(o5) << 16);
        o.w = (uint)f2bf(o6) | ((uint)f2bf(o7) << 16);
        ((uint4*)out)[(size_t)i * 16 + q] = o;
    }
}

// ---------------- pool: 1024 blocks + LDS wave-combine (131K atomics, no fence) ----
__global__ __launch_bounds__(256) void pool_kernel(const ushort* __restrict__ h,
                                                   const int* __restrict__ glo,
                                                   float* __restrict__ pools) {
    __shared__ float spool[128];
    int t = threadIdx.x, c2 = t & 63, wv = t >> 6;
    int b = blockIdx.x;
    int g = b >> 6, ch = b & 63;
    int lo = glo[g], hi = glo[g + 1];
    int span = hi - lo;
    int chunk = (span + 63) >> 6;
    int r0 = lo + ch * chunk;
    int r1 = hi < r0 + chunk ? hi : r0 + chunk;
    const uint* __restrict__ hv = (const uint*)h;

    if (t < 128) spool[t] = 0.f;
    __syncthreads();

    float a0 = 0.f, a1 = 0.f;
    #pragma unroll 4
    for (int j = r0 + wv; j < r1; j += 4) {
        uint u = hv[(size_t)j * 64 + c2];
        a0 += bf_lo(u);
        a1 += bf_hi(u);
    }
    if (r0 < r1) {
        atomicAdd(&spool[2 * c2], a0);
        atomicAdd(&spool[2 * c2 + 1], a1);
    }
    __syncthreads();
    if (t < 128) {
        float v = spool[t];
        if (v != 0.f) atomicAdd(&pools[g * 128 + t], v);
    }
}

// ---------------- final MLP head: one block ----------------
__global__ __launch_bounds__(256) void final_kernel(const int* __restrict__ glo,
                                                    const float* __restrict__ pools,
                                                    const float* __restrict__ Wf1,
                                                    const float* __restrict__ bf1,
                                                    const float* __restrict__ Wf2,
                                                    const float* __restrict__ bf2,
                                                    float* __restrict__ out) {
    __shared__ float pooled[16][128];
    __shared__ float z[16][64];
    int t = threadIdx.x;
    for (int idx = t; idx < 2048; idx += 256) {
        int gg = idx >> 7, c = idx & 127;
        int cn = glo[gg + 1] - glo[gg];
        float cnf = (float)(cn > 1 ? cn : 1);
        pooled[gg][c] = pools[idx] / cnf;
    }
    __syncthreads();
    for (int idx = t; idx < 1024; idx += 256) {
        int gg = idx >> 6, j = idx & 63;
        float s = bf1[j];
        for (int k = 0; k < 128; ++k) s = fmaf(pooled[gg][k], Wf1[k * 64 + j], s);
        z[gg][j] = fmaxf(s, 0.f);
    }
    __syncthreads();
    if (t < 160) {
        int gg = t / 10, k = t % 10;
        float s = bf2[k];
        for (int j = 0; j < 64; ++j) s = fmaf(z[gg][j], Wf2[j * 10 + k], s);
        out[t] = s;
    }
}

// ---------------- launch ----------------

extern "C" void kernel_launch(void* const* d_in, const int* in_sizes, int n_in,
                              void* d_out, int out_size, void* d_ws, size_t ws_size,
                              hipStream_t stream) {
    const float* x    = (const float*)d_in[0];
    const int* edge   = (const int*)d_in[1];   // [2,E]: src then dst
    const int* batch  = (const int*)d_in[2];
    const float* W_in = (const float*)d_in[3];
    const float* b_in = (const float*)d_in[4];
    const float* W1   = (const float*)d_in[5];
    const float* b1   = (const float*)d_in[6];
    const float* W2   = (const float*)d_in[7];
    const float* b2   = (const float*)d_in[8];
    const float* Wf1  = (const float*)d_in[9];
    const float* bf1  = (const float*)d_in[10];
    const float* Wf2  = (const float*)d_in[11];
    const float* bf2  = (const float*)d_in[12];
    float* out = (float*)d_out;

    char* ws = (char*)d_ws;
    size_t off = 0;
    auto alloc = [&](size_t bytes) -> void* {
        void* p = ws + off;
        off += (bytes + 511) & ~(size_t)511;
        return p;
    };
    // zero region: cnt + pools + {ovfcnt, glo[17]} -> one memset
    int* cnt      = (int*)alloc((size_t)NN * 4);
    float* pools  = (float*)alloc(16 * 128 * 4);
    int* misc     = (int*)alloc(512);
    size_t zero_bytes = off;
    int* ovfcnt   = misc;
    int* glo      = misc + 8;                      // 17 ints
    ushort* bufA  = (ushort*)alloc((size_t)NN * 128 * 2);   // hw1 = x@(W_in@W1)
    ushort* bufB  = (ushort*)alloc((size_t)NN * 128 * 2);   // h2 (layer-2 out)
    ushort* bufC  = (ushort*)alloc((size_t)NN * 128 * 2);   // hw2 = h1@W2
    ushort* Bp1   = (ushort*)alloc(128 * 128 * 2);
    ushort* Bp2   = (ushort*)alloc(128 * 128 * 2);
    float* cvec   = (float*)alloc(128 * 4);
    float* dis    = (float*)alloc((size_t)NN * 4);
    uint* spack   = (uint*)alloc((size_t)NN * 4);
    ushort* bucket= (ushort*)alloc((size_t)NN * 64 * 2);    // 5.12 MB
    uint* ovf     = (uint*)alloc((size_t)EE * 4);           // overflow (d | s<<16)

    hipMemsetAsync(cnt, 0, zero_bytes, stream);

    prep_kernel<<<129, 256, 0, stream>>>(W_in, W1, b_in, W2, batch, Bp1, Bp2, cvec, glo);
    fill_kernel<<<2500 + NN / 64, 256, 0, stream>>>(edge, edge + EE, cnt, ovfcnt, ovf,
                                                    bucket, x, Bp1, bufA);
    dsprep_kernel<<<NCH, 256, 0, stream>>>(cnt, dis, spack, NN);
    agg1m_kernel<<<NN / 16, 256, 0, stream>>>(bufA, dis, cnt, bucket, spack, ovf, ovfcnt,
                                              cvec, b1, Bp2, bufC);
    agg_kernel<<<NN / 4, 256, 0, stream>>>(bufC, dis, cnt, bucket, spack, ovf, ovfcnt,
                                           nullptr, b2, bufB, NN);
    pool_kernel<<<1024, 256, 0, stream>>>(bufB, glo, pools);
    final_kernel<<<1, 256, 0, stream>>>(glo, pools, Wf1, bf1, Wf2, bf2, out);
}

// Round 11
// 205.804 us; speedup vs baseline: 1.4554x; 1.0774x over previous
//
#include <hip/hip_runtime.h>
#include <hip/hip_fp16.h>

#define NN 40000
#define EE 640000
#define NCH 157   // ceil(NN/256)

typedef unsigned int uint;
typedef unsigned short ushort;
typedef __attribute__((ext_vector_type(8))) short short8;
typedef __attribute__((ext_vector_type(4))) float floatx4;
typedef __attribute__((ext_vector_type(4))) uint uint4e;

// ---- bf16 helpers (RNE) ----
__device__ inline ushort f2bf(float f) {
    uint u = __float_as_uint(f);
    return (ushort)((u + 0x7fffu + ((u >> 16) & 1u)) >> 16);
}
__device__ inline float bf_lo(uint u) { return __uint_as_float(u << 16); }
__device__ inline float bf_hi(uint u) { return __uint_as_float(u & 0xffff0000u); }

__device__ inline int lower_bound_dev(const int* __restrict__ a, int n, int x) {
    int lo = 0, hi = n;
    while (lo < hi) { int m = (lo + hi) >> 1; if (a[m] < x) lo = m + 1; else hi = m; }
    return lo;
}

// ---------------- weight prep + graph bounds (129 blocks) ----------------
__global__ __launch_bounds__(256) void prep_kernel(const float* __restrict__ W_in,
                                                   const float* __restrict__ W1,
                                                   const float* __restrict__ b_in,
                                                   const float* __restrict__ W2,
                                                   const int* __restrict__ batch,
                                                   ushort* __restrict__ Bp1,
                                                   ushort* __restrict__ Bp2,
                                                   float* __restrict__ cvec,
                                                   int* __restrict__ glo) {
    int b = blockIdx.x, t = threadIdx.x;
    if (b < 64) {
        int idx = b * 256 + t;
        int k = idx >> 7, n = idx & 127;
        float s = 0.f;
        for (int j = 0; j < 128; ++j) s = fmaf(W_in[k * 128 + j], W1[j * 128 + n], s);
        Bp1[((size_t)(k >> 3) * 128 + n) * 8 + (k & 7)] = f2bf(s);
    } else if (b < 128) {
        int idx = (b - 64) * 256 + t;
        int k = idx >> 7, n = idx & 127;
        Bp2[((size_t)(k >> 3) * 128 + n) * 8 + (k & 7)] = f2bf(W2[idx]);
    } else {
        if (t < 128) {
            float s = 0.f;
            for (int k = 0; k < 128; ++k) s = fmaf(b_in[k], W1[k * 128 + t], s);
            cvec[t] = s;
        } else if (t < 128 + 17) {
            int g = t - 128;                      // 0..16
            glo[g] = lower_bound_dev(batch, NN, g);
        }
    }
}

// ---- MFMA 64-row tile: C[64,128](bf16) = A[64,128] @ Bpack (row-major C) ----
template <bool ABF16>
__device__ inline void mm_tile(const void* __restrict__ Av, const ushort* __restrict__ Bpack,
                               ushort* __restrict__ C, int tile, int wv, int lane) {
    int m = lane & 15, q = lane >> 4;
    int row = tile * 64 + wv * 16 + m;

    short8 afr[4];
    if (ABF16) {
        const ushort* A = (const ushort*)Av;
        const ushort* ap = A + (size_t)row * 128 + q * 8;
        #pragma unroll
        for (int k0 = 0; k0 < 4; ++k0) afr[k0] = *(const short8*)(ap + k0 * 32);
    } else {
        const float* A = (const float*)Av;
        const float* ap = A + (size_t)row * 128 + q * 8;
        #pragma unroll
        for (int k0 = 0; k0 < 4; ++k0) {
            float4 f0 = *(const float4*)(ap + k0 * 32);
            float4 f1 = *(const float4*)(ap + k0 * 32 + 4);
            short8 a;
            a[0] = (short)f2bf(f0.x); a[1] = (short)f2bf(f0.y);
            a[2] = (short)f2bf(f0.z); a[3] = (short)f2bf(f0.w);
            a[4] = (short)f2bf(f1.x); a[5] = (short)f2bf(f1.y);
            a[6] = (short)f2bf(f1.z); a[7] = (short)f2bf(f1.w);
            afr[k0] = a;
        }
    }

    floatx4 acc[8];
    #pragma unroll
    for (int nt = 0; nt < 8; ++nt) { floatx4 z = {0.f, 0.f, 0.f, 0.f}; acc[nt] = z; }

    #pragma unroll
    for (int nt = 0; nt < 8; ++nt) {
        #pragma unroll
        for (int k0 = 0; k0 < 4; ++k0) {
            short8 bfrag = *(const short8*)(Bpack + ((size_t)(k0 * 4 + q) * 128 + nt * 16 + m) * 8);
            acc[nt] = __builtin_amdgcn_mfma_f32_16x16x32_bf16(afr[k0], bfrag, acc[nt], 0, 0, 0);
        }
    }

    int orow_base = tile * 64 + wv * 16 + q * 4;
    #pragma unroll
    for (int nt = 0; nt < 8; ++nt) {
        #pragma unroll
        for (int r = 0; r < 4; ++r)
            C[(size_t)(orow_base + r) * 128 + nt * 16 + m] = f2bf(acc[nt][r]);
    }
}

// ---------------- bucket fill ∪ mm1 (one launch) ----------------
// 4 edges per thread: int4 loads, 4 independent atomics in flight (the fill
// path is atomic-LATENCY-bound: R10 showed 62us at 1 atomic/thread with
// VALU 1.7%, HBM 12%). Bucket contents identical as sets; slot order differs.
__global__ __launch_bounds__(256) void fill_kernel(const int* __restrict__ src,
                                                   const int* __restrict__ dst,
                                                   int* __restrict__ cnt,
                                                   int* __restrict__ ovfcnt,
                                                   uint* __restrict__ ovf,
                                                   ushort* __restrict__ bucket,
                                                   const float* __restrict__ x,
                                                   const ushort* __restrict__ Bp1,
                                                   ushort* __restrict__ bufA) {
    int b = blockIdx.x, t = threadIdx.x;
    if (b < 625) {
        int e4 = b * 256 + t;
        int4 s4 = ((const int4*)src)[e4];
        int4 d4 = ((const int4*)dst)[e4];
        int p0 = atomicAdd(&cnt[d4.x], 1);
        int p1 = atomicAdd(&cnt[d4.y], 1);
        int p2 = atomicAdd(&cnt[d4.z], 1);
        int p3 = atomicAdd(&cnt[d4.w], 1);
        if (p0 < 64) bucket[(size_t)d4.x * 64 + p0] = (ushort)s4.x;
        else { int k = atomicAdd(ovfcnt, 1); ovf[k] = (uint)d4.x | ((uint)s4.x << 16); }
        if (p1 < 64) bucket[(size_t)d4.y * 64 + p1] = (ushort)s4.y;
        else { int k = atomicAdd(ovfcnt, 1); ovf[k] = (uint)d4.y | ((uint)s4.y << 16); }
        if (p2 < 64) bucket[(size_t)d4.z * 64 + p2] = (ushort)s4.z;
        else { int k = atomicAdd(ovfcnt, 1); ovf[k] = (uint)d4.z | ((uint)s4.z << 16); }
        if (p3 < 64) bucket[(size_t)d4.w * 64 + p3] = (ushort)s4.w;
        else { int k = atomicAdd(ovfcnt, 1); ovf[k] = (uint)d4.w | ((uint)s4.w << 16); }
    } else {
        mm_tile<false>(x, Bp1, bufA, b - 625, t >> 6, t & 63);
    }
}

// ---------------- dis + spack (elementwise, after fill) ----------------
// spack[i] = i | fp16(dis[i])<<16
__global__ __launch_bounds__(256) void dsprep_kernel(const int* __restrict__ cnt,
                                                     float* __restrict__ dis,
                                                     uint* __restrict__ spack, int N) {
    int i = blockIdx.x * 256 + threadIdx.x;
    if (i < N) {
        float dv = rsqrtf((float)cnt[i] + 1.0f);
        dis[i] = dv;
        spack[i] = (uint)i | ((uint)__half_as_ushort(__float2half_rn(dv)) << 16);
    }
}

// ---------------- layer-1: aggregation fused with @W2 (MFMA from LDS A-tile) ----
// 2500 blocks x 256 threads; 4 waves x 4 nodes -> 16-row bf16 A-tile in LDS
// (16B slots, XOR swizzle slot ^= row&7). Staging: s = bucket[i][lane],
// ed = spack[s] (low16 s, high16 fp16 dis[s]); pad ed = i (norm 0).
// dis[i] applied once after the fold. deg>64 handled via overflow list.
__global__ __launch_bounds__(256) void agg1m_kernel(const ushort* __restrict__ hw,
                                                    const float* __restrict__ dis,
                                                    const int* __restrict__ cnt,
                                                    const ushort* __restrict__ bucket,
                                                    const uint* __restrict__ spack,
                                                    const uint* __restrict__ ovf,
                                                    const int* __restrict__ ovfcnt,
                                                    const float* __restrict__ cvec,
                                                    const float* __restrict__ bias,
                                                    const ushort* __restrict__ Bp2,
                                                    ushort* __restrict__ C) {
    __shared__ ushort Atile[16][128];   // 4 KB, swizzled 16B slots
    __shared__ uint eds[4][64];
    int t = threadIdx.x;
    int wv = t >> 6, lane = t & 63;
    int qg = lane & 15, h4 = lane >> 4;   // gather roles
    const uint4* __restrict__ hv4 = (const uint4*)hw;
    int base = blockIdx.x * 16;
    char* abase = (char*)&Atile[0][0];

    for (int n = 0; n < 4; ++n) {
        int nl = wv * 4 + n;              // local row 0..15
        int i = base + nl;
        int deg = cnt[i];
        int dmain = deg > 64 ? 64 : deg;

        uint ed = (uint)i;                // pad: self row, fp16 norm bits = 0
        if (lane < dmain) ed = spack[bucket[(size_t)i * 64 + lane]];
        eds[wv][lane] = ed;

        float a0 = 0.f, a1 = 0.f, a2 = 0.f, a3 = 0.f;
        float a4 = 0.f, a5 = 0.f, a6 = 0.f, a7 = 0.f;
        float sn = 0.f;

        int dpad = (dmain + 15) & ~15;
        for (int j = 0; j < dpad; j += 16) {
            uint e0 = eds[wv][j + h4];
            uint e1 = eds[wv][j + 4 + h4];
            uint e2 = eds[wv][j + 8 + h4];
            uint e3 = eds[wv][j + 12 + h4];
            uint4 u0 = hv4[(size_t)(e0 & 0xffffu) * 16 + qg];
            uint4 u1 = hv4[(size_t)(e1 & 0xffffu) * 16 + qg];
            uint4 u2 = hv4[(size_t)(e2 & 0xffffu) * 16 + qg];
            uint4 u3 = hv4[(size_t)(e3 & 0xffffu) * 16 + qg];
            float n0 = __half2float(__ushort_as_half((ushort)(e0 >> 16)));
            float n1 = __half2float(__ushort_as_half((ushort)(e1 >> 16)));
            float n2 = __half2float(__ushort_as_half((ushort)(e2 >> 16)));
            float n3 = __half2float(__ushort_as_half((ushort)(e3 >> 16)));
            a0 = fmaf(n0, bf_lo(u0.x), a0); a1 = fmaf(n0, bf_hi(u0.x), a1);
            a2 = fmaf(n0, bf_lo(u0.y), a2); a3 = fmaf(n0, bf_hi(u0.y), a3);
            a4 = fmaf(n0, bf_lo(u0.z), a4); a5 = fmaf(n0, bf_hi(u0.z), a5);
            a6 = fmaf(n0, bf_lo(u0.w), a6); a7 = fmaf(n0, bf_hi(u0.w), a7);
            a0 = fmaf(n1, bf_lo(u1.x), a0); a1 = fmaf(n1, bf_hi(u1.x), a1);
            a2 = fmaf(n1, bf_lo(u1.y), a2); a3 = fmaf(n1, bf_hi(u1.y), a3);
            a4 = fmaf(n1, bf_lo(u1.z), a4); a5 = fmaf(n1, bf_hi(u1.z), a5);
            a6 = fmaf(n1, bf_lo(u1.w), a6); a7 = fmaf(n1, bf_hi(u1.w), a7);
            a0 = fmaf(n2, bf_lo(u2.x), a0); a1 = fmaf(n2, bf_hi(u2.x), a1);
            a2 = fmaf(n2, bf_lo(u2.y), a2); a3 = fmaf(n2, bf_hi(u2.y), a3);
            a4 = fmaf(n2, bf_lo(u2.z), a4); a5 = fmaf(n2, bf_hi(u2.z), a5);
            a6 = fmaf(n2, bf_lo(u2.w), a6); a7 = fmaf(n2, bf_hi(u2.w), a7);
            a0 = fmaf(n3, bf_lo(u3.x), a0); a1 = fmaf(n3, bf_hi(u3.x), a1);
            a2 = fmaf(n3, bf_lo(u3.y), a2); a3 = fmaf(n3, bf_hi(u3.y), a3);
            a4 = fmaf(n3, bf_lo(u3.z), a4); a5 = fmaf(n3, bf_hi(u3.z), a5);
            a6 = fmaf(n3, bf_lo(u3.w), a6); a7 = fmaf(n3, bf_hi(u3.w), a7);
            sn += (n0 + n1) + (n2 + n3);
        }
        if (deg > 64) {                    // overflow tail (wave-uniform, ~never)
            int ovfn = *ovfcnt;
            for (int k = 0; k < ovfn; ++k) {
                uint oe = ovf[k];
                if ((int)(oe & 0xffffu) == i && h4 == 0) {
                    int s2 = (int)(oe >> 16);
                    uint sp = spack[s2];
                    float n0 = __half2float(__ushort_as_half((ushort)(sp >> 16)));
                    uint4 u = hv4[(size_t)s2 * 16 + qg];
                    a0 = fmaf(n0, bf_lo(u.x), a0); a1 = fmaf(n0, bf_hi(u.x), a1);
                    a2 = fmaf(n0, bf_lo(u.y), a2); a3 = fmaf(n0, bf_hi(u.y), a3);
                    a4 = fmaf(n0, bf_lo(u.z), a4); a5 = fmaf(n0, bf_hi(u.z), a5);
                    a6 = fmaf(n0, bf_lo(u.w), a6); a7 = fmaf(n0, bf_hi(u.w), a7);
                    sn += n0;
                }
            }
        }

        a0 += __shfl_xor(a0, 16); a0 += __shfl_xor(a0, 32);
        a1 += __shfl_xor(a1, 16); a1 += __shfl_xor(a1, 32);
        a2 += __shfl_xor(a2, 16); a2 += __shfl_xor(a2, 32);
        a3 += __shfl_xor(a3, 16); a3 += __shfl_xor(a3, 32);
        a4 += __shfl_xor(a4, 16); a4 += __shfl_xor(a4, 32);
        a5 += __shfl_xor(a5, 16); a5 += __shfl_xor(a5, 32);
        a6 += __shfl_xor(a6, 16); a6 += __shfl_xor(a6, 32);
        a7 += __shfl_xor(a7, 16); a7 += __shfl_xor(a7, 32);
        sn += __shfl_xor(sn, 16); sn += __shfl_xor(sn, 32);

        // apply dis[i] (factored out of edge loop), then self-loop term
        float di = dis[i];
        float sii = di * di;
        a0 *= di; a1 *= di; a2 *= di; a3 *= di;
        a4 *= di; a5 *= di; a6 *= di; a7 *= di;
        sn *= di;
        uint4 su = hv4[(size_t)i * 16 + qg];
        a0 = fmaf(sii, bf_lo(su.x), a0); a1 = fmaf(sii, bf_hi(su.x), a1);
        a2 = fmaf(sii, bf_lo(su.y), a2); a3 = fmaf(sii, bf_hi(su.y), a3);
        a4 = fmaf(sii, bf_lo(su.z), a4); a5 = fmaf(sii, bf_hi(su.z), a5);
        a6 = fmaf(sii, bf_lo(su.w), a6); a7 = fmaf(sii, bf_hi(su.w), a7);
        sn += sii;

        float4 ca = *(const float4*)(cvec + 8 * qg);
        float4 cb = *(const float4*)(cvec + 8 * qg + 4);
        float4 ba = *(const float4*)(bias + 8 * qg);
        float4 bb = *(const float4*)(bias + 8 * qg + 4);
        float o0 = fmaxf(fmaf(sn, ca.x, a0) + ba.x, 0.f);
        float o1 = fmaxf(fmaf(sn, ca.y, a1) + ba.y, 0.f);
        float o2 = fmaxf(fmaf(sn, ca.z, a2) + ba.z, 0.f);
        float o3 = fmaxf(fmaf(sn, ca.w, a3) + ba.w, 0.f);
        float o4 = fmaxf(fmaf(sn, cb.x, a4) + bb.x, 0.f);
        float o5 = fmaxf(fmaf(sn, cb.y, a5) + bb.y, 0.f);
        float o6 = fmaxf(fmaf(sn, cb.z, a6) + bb.z, 0.f);
        float o7 = fmaxf(fmaf(sn, cb.w, a7) + bb.w, 0.f);

        if (h4 == 0) {
            uint4e o;
            o.x = (uint)f2bf(o0) | ((uint)f2bf(o1) << 16);
            o.y = (uint)f2bf(o2) | ((uint)f2bf(o3) << 16);
            o.z = (uint)f2bf(o4) | ((uint)f2bf(o5) << 16);
            o.w = (uint)f2bf(o6) | ((uint)f2bf(o7) << 16);
            int slot = qg ^ (nl & 7);
            *(uint4e*)(abase + nl * 256 + slot * 16) = o;
        }
    }

    __syncthreads();

    {
        int m = lane & 15, qm = lane >> 4;
        short8 afr[4];
        #pragma unroll
        for (int k0 = 0; k0 < 4; ++k0) {
            int slot = (qm + 4 * k0) ^ (m & 7);
            afr[k0] = *(const short8*)(abase + m * 256 + slot * 16);
        }
        floatx4 acc[2];
        #pragma unroll
        for (int u = 0; u < 2; ++u) { floatx4 z = {0.f, 0.f, 0.f, 0.f}; acc[u] = z; }
        #pragma unroll
        for (int u = 0; u < 2; ++u) {
            int nt = 2 * wv + u;
            #pragma unroll
            for (int k0 = 0; k0 < 4; ++k0) {
                short8 bfrag = *(const short8*)(Bp2 + ((size_t)(k0 * 4 + qm) * 128 + nt * 16 + m) * 8);
                acc[u] = __builtin_amdgcn_mfma_f32_16x16x32_bf16(afr[k0], bfrag, acc[u], 0, 0, 0);
            }
        }
        int orow_base = base + qm * 4;
        #pragma unroll
        for (int u = 0; u < 2; ++u) {
            int nt = 2 * wv + u;
            #pragma unroll
            for (int r = 0; r < 4; ++r)
                C[(size_t)(orow_base + r) * 128 + nt * 16 + m] = f2bf(acc[u][r]);
        }
    }
}

// ---------------- GCN aggregation (layer 2): one wave per dst node ----------------
__global__ __launch_bounds__(256) void agg_kernel(const ushort* __restrict__ hw,
                                                  const float* __restrict__ dis,
                                                  const int* __restrict__ cnt,
                                                  const ushort* __restrict__ bucket,
                                                  const uint* __restrict__ spack,
                                                  const uint* __restrict__ ovf,
                                                  const int* __restrict__ ovfcnt,
                                                  const float* __restrict__ cvec,
                                                  const float* __restrict__ bias,
                                                  ushort* __restrict__ out, int N) {
    __shared__ uint eds[4][64];
    int wv = threadIdx.x >> 6;
    int lane = threadIdx.x & 63;
    int q = lane & 15, h4 = lane >> 4;
    int i = blockIdx.x * 4 + wv;
    if (i >= N) return;
    int deg = cnt[i];
    int dmain = deg > 64 ? 64 : deg;
    const uint4* __restrict__ hv4 = (const uint4*)hw;

    uint ed = (uint)i;
    if (lane < dmain) ed = spack[bucket[(size_t)i * 64 + lane]];
    eds[wv][lane] = ed;

    float a0 = 0.f, a1 = 0.f, a2 = 0.f, a3 = 0.f;
    float a4 = 0.f, a5 = 0.f, a6 = 0.f, a7 = 0.f;
    float sn = 0.f;

    int dpad = (dmain + 15) & ~15;
    for (int j = 0; j < dpad; j += 16) {
        uint e0 = eds[wv][j + h4];
        uint e1 = eds[wv][j + 4 + h4];
        uint e2 = eds[wv][j + 8 + h4];
        uint e3 = eds[wv][j + 12 + h4];
        uint4 u0 = hv4[(size_t)(e0 & 0xffffu) * 16 + q];
        uint4 u1 = hv4[(size_t)(e1 & 0xffffu) * 16 + q];
        uint4 u2 = hv4[(size_t)(e2 & 0xffffu) * 16 + q];
        uint4 u3 = hv4[(size_t)(e3 & 0xffffu) * 16 + q];
        float n0 = __half2float(__ushort_as_half((ushort)(e0 >> 16)));
        float n1 = __half2float(__ushort_as_half((ushort)(e1 >> 16)));
        float n2 = __half2float(__ushort_as_half((ushort)(e2 >> 16)));
        float n3 = __half2float(__ushort_as_half((ushort)(e3 >> 16)));
        a0 = fmaf(n0, bf_lo(u0.x), a0); a1 = fmaf(n0, bf_hi(u0.x), a1);
        a2 = fmaf(n0, bf_lo(u0.y), a2); a3 = fmaf(n0, bf_hi(u0.y), a3);
        a4 = fmaf(n0, bf_lo(u0.z), a4); a5 = fmaf(n0, bf_hi(u0.z), a5);
        a6 = fmaf(n0, bf_lo(u0.w), a6); a7 = fmaf(n0, bf_hi(u0.w), a7);
        a0 = fmaf(n1, bf_lo(u1.x), a0); a1 = fmaf(n1, bf_hi(u1.x), a1);
        a2 = fmaf(n1, bf_lo(u1.y), a2); a3 = fmaf(n1, bf_hi(u1.y), a3);
        a4 = fmaf(n1, bf_lo(u1.z), a4); a5 = fmaf(n1, bf_hi(u1.z), a5);
        a6 = fmaf(n1, bf_lo(u1.w), a6); a7 = fmaf(n1, bf_hi(u1.w), a7);
        a0 = fmaf(n2, bf_lo(u2.x), a0); a1 = fmaf(n2, bf_hi(u2.x), a1);
        a2 = fmaf(n2, bf_lo(u2.y), a2); a3 = fmaf(n2, bf_hi(u2.y), a3);
        a4 = fmaf(n2, bf_lo(u2.z), a4); a5 = fmaf(n2, bf_hi(u2.z), a5);
        a6 = fmaf(n2, bf_lo(u2.w), a6); a7 = fmaf(n2, bf_hi(u2.w), a7);
        a0 = fmaf(n3, bf_lo(u3.x), a0); a1 = fmaf(n3, bf_hi(u3.x), a1);
        a2 = fmaf(n3, bf_lo(u3.y), a2); a3 = fmaf(n3, bf_hi(u3.y), a3);
        a4 = fmaf(n3, bf_lo(u3.z), a4); a5 = fmaf(n3, bf_hi(u3.z), a5);
        a6 = fmaf(n3, bf_lo(u3.w), a6); a7 = fmaf(n3, bf_hi(u3.w), a7);
        sn += (n0 + n1) + (n2 + n3);
    }
    if (deg > 64) {                        // overflow tail (wave-uniform, ~never)
        int ovfn = *ovfcnt;
        for (int k = 0; k < ovfn; ++k) {
            uint oe = ovf[k];
            if ((int)(oe & 0xffffu) == i && h4 == 0) {
                int s2 = (int)(oe >> 16);
                uint sp = spack[s2];
                float n0 = __half2float(__ushort_as_half((ushort)(sp >> 16)));
                uint4 u = hv4[(size_t)s2 * 16 + q];
                a0 = fmaf(n0, bf_lo(u.x), a0); a1 = fmaf(n0, bf_hi(u.x), a1);
                a2 = fmaf(n0, bf_lo(u.y), a2); a3 = fmaf(n0, bf_hi(u.y), a3);
                a4 = fmaf(n0, bf_lo(u.z), a4); a5 = fmaf(n0, bf_hi(u.z), a5);
                a6 = fmaf(n0, bf_lo(u.w), a6); a7 = fmaf(n0, bf_hi(u.w), a7);
                sn += n0;
            }
        }
    }

    a0 += __shfl_xor(a0, 16); a0 += __shfl_xor(a0, 32);
    a1 += __shfl_xor(a1, 16); a1 += __shfl_xor(a1, 32);
    a2 += __shfl_xor(a2, 16); a2 += __shfl_xor(a2, 32);
    a3 += __shfl_xor(a3, 16); a3 += __shfl_xor(a3, 32);
    a4 += __shfl_xor(a4, 16); a4 += __shfl_xor(a4, 32);
    a5 += __shfl_xor(a5, 16); a5 += __shfl_xor(a5, 32);
    a6 += __shfl_xor(a6, 16); a6 += __shfl_xor(a6, 32);
    a7 += __shfl_xor(a7, 16); a7 += __shfl_xor(a7, 32);
    sn += __shfl_xor(sn, 16); sn += __shfl_xor(sn, 32);

    // apply dis[i] (factored out of edge loop), then self-loop term
    float di = dis[i];
    float sii = di * di;
    a0 *= di; a1 *= di; a2 *= di; a3 *= di;
    a4 *= di; a5 *= di; a6 *= di; a7 *= di;
    sn *= di;
    uint4 su = hv4[(size_t)i * 16 + q];
    a0 = fmaf(sii, bf_lo(su.x), a0); a1 = fmaf(sii, bf_hi(su.x), a1);
    a2 = fmaf(sii, bf_lo(su.y), a2); a3 = fmaf(sii, bf_hi(su.y), a3);
    a4 = fmaf(sii, bf_lo(su.z), a4); a5 = fmaf(sii, bf_hi(su.z), a5);
    a6 = fmaf(sii, bf_lo(su.w), a6); a7 = fmaf(sii, bf_hi(su.w), a7);
    sn += sii;

    float c0 = 0.f, c1 = 0.f, c2 = 0.f, c3 = 0.f;
    float c4 = 0.f, c5 = 0.f, c6 = 0.f, c7 = 0.f;
    if (cvec) {
        float4 ca = *(const float4*)(cvec + 8 * q);
        float4 cb = *(const float4*)(cvec + 8 * q + 4);
        c0 = ca.x; c1 = ca.y; c2 = ca.z; c3 = ca.w;
        c4 = cb.x; c5 = cb.y; c6 = cb.z; c7 = cb.w;
    }
    float4 ba = *(const float4*)(bias + 8 * q);
    float4 bb = *(const float4*)(bias + 8 * q + 4);
    float o0 = fmaxf(fmaf(sn, c0, a0) + ba.x, 0.f);
    float o1 = fmaxf(fmaf(sn, c1, a1) + ba.y, 0.f);
    float o2 = fmaxf(fmaf(sn, c2, a2) + ba.z, 0.f);
    float o3 = fmaxf(fmaf(sn, c3, a3) + ba.w, 0.f);
    float o4 = fmaxf(fmaf(sn, c4, a4) + bb.x, 0.f);
    float o5 = fmaxf(fmaf(sn, c5, a5) + bb.y, 0.f);
    float o6 = fmaxf(fmaf(sn, c6, a6) + bb.z, 0.f);
    float o7 = fmaxf(fmaf(sn, c7, a7) + bb.w, 0.f);
    if (h4 == 0) {
        uint4 o;
        o.x = (uint)f2bf(o0) | ((uint)f2bf(o1) << 16);
        o.y = (uint)f2bf(o2) | ((uint)f2bf(o3) << 16);
        o.z = (uint)f2bf(o4) | ((uint)f2bf(o5) << 16);
        o.w = (uint)f2bf(o6) | ((uint)f2bf(o7) << 16);
        ((uint4*)out)[(size_t)i * 16 + q] = o;
    }
}

// ---------------- pool: 1024 blocks + LDS wave-combine (131K atomics, no fence) ----
__global__ __launch_bounds__(256) void pool_kernel(const ushort* __restrict__ h,
                                                   const int* __restrict__ glo,
                                                   float* __restrict__ pools) {
    __shared__ float spool[128];
    int t = threadIdx.x, c2 = t & 63, wv = t >> 6;
    int b = blockIdx.x;
    int g = b >> 6, ch = b & 63;
    int lo = glo[g], hi = glo[g + 1];
    int span = hi - lo;
    int chunk = (span + 63) >> 6;
    int r0 = lo + ch * chunk;
    int r1 = hi < r0 + chunk ? hi : r0 + chunk;
    const uint* __restrict__ hv = (const uint*)h;

    if (t < 128) spool[t] = 0.f;
    __syncthreads();

    float a0 = 0.f, a1 = 0.f;
    #pragma unroll 4
    for (int j = r0 + wv; j < r1; j += 4) {
        uint u = hv[(size_t)j * 64 + c2];
        a0 += bf_lo(u);
        a1 += bf_hi(u);
    }
    if (r0 < r1) {
        atomicAdd(&spool[2 * c2], a0);
        atomicAdd(&spool[2 * c2 + 1], a1);
    }
    __syncthreads();
    if (t < 128) {
        float v = spool[t];
        if (v != 0.f) atomicAdd(&pools[g * 128 + t], v);
    }
}

// ---------------- final MLP head: one block ----------------
__global__ __launch_bounds__(256) void final_kernel(const int* __restrict__ glo,
                                                    const float* __restrict__ pools,
                                                    const float* __restrict__ Wf1,
                                                    const float* __restrict__ bf1,
                                                    const float* __restrict__ Wf2,
                                                    const float* __restrict__ bf2,
                                                    float* __restrict__ out) {
    __shared__ float pooled[16][128];
    __shared__ float z[16][64];
    int t = threadIdx.x;
    for (int idx = t; idx < 2048; idx += 256) {
        int gg = idx >> 7, c = idx & 127;
        int cn = glo[gg + 1] - glo[gg];
        float cnf = (float)(cn > 1 ? cn : 1);
        pooled[gg][c] = pools[idx] / cnf;
    }
    __syncthreads();
    for (int idx = t; idx < 1024; idx += 256) {
        int gg = idx >> 6, j = idx & 63;
        float s = bf1[j];
        for (int k = 0; k < 128; ++k) s = fmaf(pooled[gg][k], Wf1[k * 64 + j], s);
        z[gg][j] = fmaxf(s, 0.f);
    }
    __syncthreads();
    if (t < 160) {
        int gg = t / 10, k = t % 10;
        float s = bf2[k];
        for (int j = 0; j < 64; ++j) s = fmaf(z[gg][j], Wf2[j * 10 + k], s);
        out[t] = s;
    }
}

// ---------------- launch ----------------

extern "C" void kernel_launch(void* const* d_in, const int* in_sizes, int n_in,
                              void* d_out, int out_size, void* d_ws, size_t ws_size,
                              hipStream_t stream) {
    const float* x    = (const float*)d_in[0];
    const int* edge   = (const int*)d_in[1];   // [2,E]: src then dst
    const int* batch  = (const int*)d_in[2];
    const float* W_in = (const float*)d_in[3];
    const float* b_in = (const float*)d_in[4];
    const float* W1   = (const float*)d_in[5];
    const float* b1   = (const float*)d_in[6];
    const float* W2   = (const float*)d_in[7];
    const float* b2   = (const float*)d_in[8];
    const float* Wf1  = (const float*)d_in[9];
    const float* bf1  = (const float*)d_in[10];
    const float* Wf2  = (const float*)d_in[11];
    const float* bf2  = (const float*)d_in[12];
    float* out = (float*)d_out;

    char* ws = (char*)d_ws;
    size_t off = 0;
    auto alloc = [&](size_t bytes) -> void* {
        void* p = ws + off;
        off += (bytes + 511) & ~(size_t)511;
        return p;
    };
    // zero region: cnt + pools + {ovfcnt, glo[17]} -> one memset
    int* cnt      = (int*)alloc((size_t)NN * 4);
    float* pools  = (float*)alloc(16 * 128 * 4);
    int* misc     = (int*)alloc(512);
    size_t zero_bytes = off;
    int* ovfcnt   = misc;
    int* glo      = misc + 8;                      // 17 ints
    ushort* bufA  = (ushort*)alloc((size_t)NN * 128 * 2);   // hw1 = x@(W_in@W1)
    ushort* bufB  = (ushort*)alloc((size_t)NN * 128 * 2);   // h2 (layer-2 out)
    ushort* bufC  = (ushort*)alloc((size_t)NN * 128 * 2);   // hw2 = h1@W2
    ushort* Bp1   = (ushort*)alloc(128 * 128 * 2);
    ushort* Bp2   = (ushort*)alloc(128 * 128 * 2);
    float* cvec   = (float*)alloc(128 * 4);
    float* dis    = (float*)alloc((size_t)NN * 4);
    uint* spack   = (uint*)alloc((size_t)NN * 4);
    ushort* bucket= (ushort*)alloc((size_t)NN * 64 * 2);    // 5.12 MB
    uint* ovf     = (uint*)alloc((size_t)EE * 4);           // overflow (d | s<<16)

    hipMemsetAsync(cnt, 0, zero_bytes, stream);

    prep_kernel<<<129, 256, 0, stream>>>(W_in, W1, b_in, W2, batch, Bp1, Bp2, cvec, glo);
    fill_kernel<<<625 + NN / 64, 256, 0, stream>>>(edge, edge + EE, cnt, ovfcnt, ovf,
                                                   bucket, x, Bp1, bufA);
    dsprep_kernel<<<NCH, 256, 0, stream>>>(cnt, dis, spack, NN);
    agg1m_kernel<<<NN / 16, 256, 0, stream>>>(bufA, dis, cnt, bucket, spack, ovf, ovfcnt,
                                              cvec, b1, Bp2, bufC);
    agg_kernel<<<NN / 4, 256, 0, stream>>>(bufC, dis, cnt, bucket, spack, ovf, ovfcnt,
                                           nullptr, b2, bufB, NN);
    pool_kernel<<<1024, 256, 0, stream>>>(bufB, glo, pools);
    final_kernel<<<1, 256, 0, stream>>>(glo, pools, Wf1, bf1, Wf2, bf2, out);
}

// Round 12
// 204.333 us; speedup vs baseline: 1.4659x; 1.0072x over previous
//
#include <hip/hip_runtime.h>
#include <hip/hip_fp16.h>

#define NN 40000
#define EE 640000
#define NCH 157   // ceil(NN/256)

typedef unsigned int uint;
typedef unsigned short ushort;
typedef __attribute__((ext_vector_type(8))) short short8;
typedef __attribute__((ext_vector_type(4))) float floatx4;
typedef __attribute__((ext_vector_type(4))) uint uint4e;

// ---- bf16 helpers (RNE) ----
__device__ inline ushort f2bf(float f) {
    uint u = __float_as_uint(f);
    return (ushort)((u + 0x7fffu + ((u >> 16) & 1u)) >> 16);
}
__device__ inline float bf_lo(uint u) { return __uint_as_float(u << 16); }
__device__ inline float bf_hi(uint u) { return __uint_as_float(u & 0xffff0000u); }

__device__ inline int lower_bound_dev(const int* __restrict__ a, int n, int x) {
    int lo = 0, hi = n;
    while (lo < hi) { int m = (lo + hi) >> 1; if (a[m] < x) lo = m + 1; else hi = m; }
    return lo;
}

// ---------------- weight prep + graph bounds (129 blocks) ----------------
__global__ __launch_bounds__(256) void prep_kernel(const float* __restrict__ W_in,
                                                   const float* __restrict__ W1,
                                                   const float* __restrict__ b_in,
                                                   const float* __restrict__ W2,
                                                   const int* __restrict__ batch,
                                                   ushort* __restrict__ Bp1,
                                                   ushort* __restrict__ Bp2,
                                                   float* __restrict__ cvec,
                                                   int* __restrict__ glo) {
    int b = blockIdx.x, t = threadIdx.x;
    if (b < 64) {
        int idx = b * 256 + t;
        int k = idx >> 7, n = idx & 127;
        float s = 0.f;
        for (int j = 0; j < 128; ++j) s = fmaf(W_in[k * 128 + j], W1[j * 128 + n], s);
        Bp1[((size_t)(k >> 3) * 128 + n) * 8 + (k & 7)] = f2bf(s);
    } else if (b < 128) {
        int idx = (b - 64) * 256 + t;
        int k = idx >> 7, n = idx & 127;
        Bp2[((size_t)(k >> 3) * 128 + n) * 8 + (k & 7)] = f2bf(W2[idx]);
    } else {
        if (t < 128) {
            float s = 0.f;
            for (int k = 0; k < 128; ++k) s = fmaf(b_in[k], W1[k * 128 + t], s);
            cvec[t] = s;
        } else if (t < 128 + 17) {
            int g = t - 128;                      // 0..16
            glo[g] = lower_bound_dev(batch, NN, g);
        }
    }
}

// ---- MFMA 64-row tile: C[64,128](bf16) = A[64,128] @ Bpack (row-major C) ----
template <bool ABF16>
__device__ inline void mm_tile(const void* __restrict__ Av, const ushort* __restrict__ Bpack,
                               ushort* __restrict__ C, int tile, int wv, int lane) {
    int m = lane & 15, q = lane >> 4;
    int row = tile * 64 + wv * 16 + m;

    short8 afr[4];
    if (ABF16) {
        const ushort* A = (const ushort*)Av;
        const ushort* ap = A + (size_t)row * 128 + q * 8;
        #pragma unroll
        for (int k0 = 0; k0 < 4; ++k0) afr[k0] = *(const short8*)(ap + k0 * 32);
    } else {
        const float* A = (const float*)Av;
        const float* ap = A + (size_t)row * 128 + q * 8;
        #pragma unroll
        for (int k0 = 0; k0 < 4; ++k0) {
            float4 f0 = *(const float4*)(ap + k0 * 32);
            float4 f1 = *(const float4*)(ap + k0 * 32 + 4);
            short8 a;
            a[0] = (short)f2bf(f0.x); a[1] = (short)f2bf(f0.y);
            a[2] = (short)f2bf(f0.z); a[3] = (short)f2bf(f0.w);
            a[4] = (short)f2bf(f1.x); a[5] = (short)f2bf(f1.y);
            a[6] = (short)f2bf(f1.z); a[7] = (short)f2bf(f1.w);
            afr[k0] = a;
        }
    }

    floatx4 acc[8];
    #pragma unroll
    for (int nt = 0; nt < 8; ++nt) { floatx4 z = {0.f, 0.f, 0.f, 0.f}; acc[nt] = z; }

    #pragma unroll
    for (int nt = 0; nt < 8; ++nt) {
        #pragma unroll
        for (int k0 = 0; k0 < 4; ++k0) {
            short8 bfrag = *(const short8*)(Bpack + ((size_t)(k0 * 4 + q) * 128 + nt * 16 + m) * 8);
            acc[nt] = __builtin_amdgcn_mfma_f32_16x16x32_bf16(afr[k0], bfrag, acc[nt], 0, 0, 0);
        }
    }

    int orow_base = tile * 64 + wv * 16 + q * 4;
    #pragma unroll
    for (int nt = 0; nt < 8; ++nt) {
        #pragma unroll
        for (int r = 0; r < 4; ++r)
            C[(size_t)(orow_base + r) * 128 + nt * 16 + m] = f2bf(acc[nt][r]);
    }
}

// ---------------- bucket fill ∪ mm1 (one launch) ----------------
// 8 edges per thread: 2x int4 loads per array, 8 independent atomics in
// flight (fill is atomic-throughput/latency bound: R10 62us @1/thread,
// R11 48us @4/thread). Bucket contents identical as sets; slot order differs.
__global__ __launch_bounds__(256) void fill_kernel(const int* __restrict__ src,
                                                   const int* __restrict__ dst,
                                                   int* __restrict__ cnt,
                                                   int* __restrict__ ovfcnt,
                                                   uint* __restrict__ ovf,
                                                   ushort* __restrict__ bucket,
                                                   const float* __restrict__ x,
                                                   const ushort* __restrict__ Bp1,
                                                   ushort* __restrict__ bufA) {
    int b = blockIdx.x, t = threadIdx.x;
    if (b < 313) {
        int e8 = b * 256 + t;
        if (e8 < EE / 8) {
            int4 sa = ((const int4*)src)[e8 * 2];
            int4 sb = ((const int4*)src)[e8 * 2 + 1];
            int4 da = ((const int4*)dst)[e8 * 2];
            int4 db = ((const int4*)dst)[e8 * 2 + 1];
            int p0 = atomicAdd(&cnt[da.x], 1);
            int p1 = atomicAdd(&cnt[da.y], 1);
            int p2 = atomicAdd(&cnt[da.z], 1);
            int p3 = atomicAdd(&cnt[da.w], 1);
            int p4 = atomicAdd(&cnt[db.x], 1);
            int p5 = atomicAdd(&cnt[db.y], 1);
            int p6 = atomicAdd(&cnt[db.z], 1);
            int p7 = atomicAdd(&cnt[db.w], 1);
            if (p0 < 64) bucket[(size_t)da.x * 64 + p0] = (ushort)sa.x;
            else { int k = atomicAdd(ovfcnt, 1); ovf[k] = (uint)da.x | ((uint)sa.x << 16); }
            if (p1 < 64) bucket[(size_t)da.y * 64 + p1] = (ushort)sa.y;
            else { int k = atomicAdd(ovfcnt, 1); ovf[k] = (uint)da.y | ((uint)sa.y << 16); }
            if (p2 < 64) bucket[(size_t)da.z * 64 + p2] = (ushort)sa.z;
            else { int k = atomicAdd(ovfcnt, 1); ovf[k] = (uint)da.z | ((uint)sa.z << 16); }
            if (p3 < 64) bucket[(size_t)da.w * 64 + p3] = (ushort)sa.w;
            else { int k = atomicAdd(ovfcnt, 1); ovf[k] = (uint)da.w | ((uint)sa.w << 16); }
            if (p4 < 64) bucket[(size_t)db.x * 64 + p4] = (ushort)sb.x;
            else { int k = atomicAdd(ovfcnt, 1); ovf[k] = (uint)db.x | ((uint)sb.x << 16); }
            if (p5 < 64) bucket[(size_t)db.y * 64 + p5] = (ushort)sb.y;
            else { int k = atomicAdd(ovfcnt, 1); ovf[k] = (uint)db.y | ((uint)sb.y << 16); }
            if (p6 < 64) bucket[(size_t)db.z * 64 + p6] = (ushort)sb.z;
            else { int k = atomicAdd(ovfcnt, 1); ovf[k] = (uint)db.z | ((uint)sb.z << 16); }
            if (p7 < 64) bucket[(size_t)db.w * 64 + p7] = (ushort)sb.w;
            else { int k = atomicAdd(ovfcnt, 1); ovf[k] = (uint)db.w | ((uint)sb.w << 16); }
        }
    } else {
        mm_tile<false>(x, Bp1, bufA, b - 313, t >> 6, t & 63);
    }
}

// ---------------- dis + spack (elementwise, after fill) ----------------
// spack[i] = i | fp16(dis[i])<<16
__global__ __launch_bounds__(256) void dsprep_kernel(const int* __restrict__ cnt,
                                                     float* __restrict__ dis,
                                                     uint* __restrict__ spack, int N) {
    int i = blockIdx.x * 256 + threadIdx.x;
    if (i < N) {
        float dv = rsqrtf((float)cnt[i] + 1.0f);
        dis[i] = dv;
        spack[i] = (uint)i | ((uint)__half_as_ushort(__float2half_rn(dv)) << 16);
    }
}

// ---------------- layer-1: aggregation fused with @W2 (MFMA from LDS A-tile) ----
// 2500 blocks x 256 threads; 4 waves x 4 nodes -> 16-row bf16 A-tile in LDS
// (16B slots, XOR swizzle slot ^= row&7). Staging: s = bucket[i][lane],
// ed = spack[s] (low16 s, high16 fp16 dis[s]); pad ed = i (norm 0).
// dis[i] applied once after the fold. deg>64 handled via overflow list.
__global__ __launch_bounds__(256) void agg1m_kernel(const ushort* __restrict__ hw,
                                                    const float* __restrict__ dis,
                                                    const int* __restrict__ cnt,
                                                    const ushort* __restrict__ bucket,
                                                    const uint* __restrict__ spack,
                                                    const uint* __restrict__ ovf,
                                                    const int* __restrict__ ovfcnt,
                                                    const float* __restrict__ cvec,
                                                    const float* __restrict__ bias,
                                                    const ushort* __restrict__ Bp2,
                                                    ushort* __restrict__ C) {
    __shared__ ushort Atile[16][128];   // 4 KB, swizzled 16B slots
    __shared__ uint eds[4][64];
    int t = threadIdx.x;
    int wv = t >> 6, lane = t & 63;
    int qg = lane & 15, h4 = lane >> 4;   // gather roles
    const uint4* __restrict__ hv4 = (const uint4*)hw;
    int base = blockIdx.x * 16;
    char* abase = (char*)&Atile[0][0];

    for (int n = 0; n < 4; ++n) {
        int nl = wv * 4 + n;              // local row 0..15
        int i = base + nl;
        int deg = cnt[i];
        int dmain = deg > 64 ? 64 : deg;

        uint ed = (uint)i;                // pad: self row, fp16 norm bits = 0
        if (lane < dmain) ed = spack[bucket[(size_t)i * 64 + lane]];
        eds[wv][lane] = ed;

        float a0 = 0.f, a1 = 0.f, a2 = 0.f, a3 = 0.f;
        float a4 = 0.f, a5 = 0.f, a6 = 0.f, a7 = 0.f;
        float sn = 0.f;

        int dpad = (dmain + 15) & ~15;
        for (int j = 0; j < dpad; j += 16) {
            uint e0 = eds[wv][j + h4];
            uint e1 = eds[wv][j + 4 + h4];
            uint e2 = eds[wv][j + 8 + h4];
            uint e3 = eds[wv][j + 12 + h4];
            uint4 u0 = hv4[(size_t)(e0 & 0xffffu) * 16 + qg];
            uint4 u1 = hv4[(size_t)(e1 & 0xffffu) * 16 + qg];
            uint4 u2 = hv4[(size_t)(e2 & 0xffffu) * 16 + qg];
            uint4 u3 = hv4[(size_t)(e3 & 0xffffu) * 16 + qg];
            float n0 = __half2float(__ushort_as_half((ushort)(e0 >> 16)));
            float n1 = __half2float(__ushort_as_half((ushort)(e1 >> 16)));
            float n2 = __half2float(__ushort_as_half((ushort)(e2 >> 16)));
            float n3 = __half2float(__ushort_as_half((ushort)(e3 >> 16)));
            a0 = fmaf(n0, bf_lo(u0.x), a0); a1 = fmaf(n0, bf_hi(u0.x), a1);
            a2 = fmaf(n0, bf_lo(u0.y), a2); a3 = fmaf(n0, bf_hi(u0.y), a3);
            a4 = fmaf(n0, bf_lo(u0.z), a4); a5 = fmaf(n0, bf_hi(u0.z), a5);
            a6 = fmaf(n0, bf_lo(u0.w), a6); a7 = fmaf(n0, bf_hi(u0.w), a7);
            a0 = fmaf(n1, bf_lo(u1.x), a0); a1 = fmaf(n1, bf_hi(u1.x), a1);
            a2 = fmaf(n1, bf_lo(u1.y), a2); a3 = fmaf(n1, bf_hi(u1.y), a3);
            a4 = fmaf(n1, bf_lo(u1.z), a4); a5 = fmaf(n1, bf_hi(u1.z), a5);
            a6 = fmaf(n1, bf_lo(u1.w), a6); a7 = fmaf(n1, bf_hi(u1.w), a7);
            a0 = fmaf(n2, bf_lo(u2.x), a0); a1 = fmaf(n2, bf_hi(u2.x), a1);
            a2 = fmaf(n2, bf_lo(u2.y), a2); a3 = fmaf(n2, bf_hi(u2.y), a3);
            a4 = fmaf(n2, bf_lo(u2.z), a4); a5 = fmaf(n2, bf_hi(u2.z), a5);
            a6 = fmaf(n2, bf_lo(u2.w), a6); a7 = fmaf(n2, bf_hi(u2.w), a7);
            a0 = fmaf(n3, bf_lo(u3.x), a0); a1 = fmaf(n3, bf_hi(u3.x), a1);
            a2 = fmaf(n3, bf_lo(u3.y), a2); a3 = fmaf(n3, bf_hi(u3.y), a3);
            a4 = fmaf(n3, bf_lo(u3.z), a4); a5 = fmaf(n3, bf_hi(u3.z), a5);
            a6 = fmaf(n3, bf_lo(u3.w), a6); a7 = fmaf(n3, bf_hi(u3.w), a7);
            sn += (n0 + n1) + (n2 + n3);
        }
        if (deg > 64) {                    // overflow tail (wave-uniform, ~never)
            int ovfn = *ovfcnt;
            for (int k = 0; k < ovfn; ++k) {
                uint oe = ovf[k];
                if ((int)(oe & 0xffffu) == i && h4 == 0) {
                    int s2 = (int)(oe >> 16);
                    uint sp = spack[s2];
                    float n0 = __half2float(__ushort_as_half((ushort)(sp >> 16)));
                    uint4 u = hv4[(size_t)s2 * 16 + qg];
                    a0 = fmaf(n0, bf_lo(u.x), a0); a1 = fmaf(n0, bf_hi(u.x), a1);
                    a2 = fmaf(n0, bf_lo(u.y), a2); a3 = fmaf(n0, bf_hi(u.y), a3);
                    a4 = fmaf(n0, bf_lo(u.z), a4); a5 = fmaf(n0, bf_hi(u.z), a5);
                    a6 = fmaf(n0, bf_lo(u.w), a6); a7 = fmaf(n0, bf_hi(u.w), a7);
                    sn += n0;
                }
            }
        }

        a0 += __shfl_xor(a0, 16); a0 += __shfl_xor(a0, 32);
        a1 += __shfl_xor(a1, 16); a1 += __shfl_xor(a1, 32);
        a2 += __shfl_xor(a2, 16); a2 += __shfl_xor(a2, 32);
        a3 += __shfl_xor(a3, 16); a3 += __shfl_xor(a3, 32);
        a4 += __shfl_xor(a4, 16); a4 += __shfl_xor(a4, 32);
        a5 += __shfl_xor(a5, 16); a5 += __shfl_xor(a5, 32);
        a6 += __shfl_xor(a6, 16); a6 += __shfl_xor(a6, 32);
        a7 += __shfl_xor(a7, 16); a7 += __shfl_xor(a7, 32);
        sn += __shfl_xor(sn, 16); sn += __shfl_xor(sn, 32);

        // apply dis[i] (factored out of edge loop), then self-loop term
        float di = dis[i];
        float sii = di * di;
        a0 *= di; a1 *= di; a2 *= di; a3 *= di;
        a4 *= di; a5 *= di; a6 *= di; a7 *= di;
        sn *= di;
        uint4 su = hv4[(size_t)i * 16 + qg];
        a0 = fmaf(sii, bf_lo(su.x), a0); a1 = fmaf(sii, bf_hi(su.x), a1);
        a2 = fmaf(sii, bf_lo(su.y), a2); a3 = fmaf(sii, bf_hi(su.y), a3);
        a4 = fmaf(sii, bf_lo(su.z), a4); a5 = fmaf(sii, bf_hi(su.z), a5);
        a6 = fmaf(sii, bf_lo(su.w), a6); a7 = fmaf(sii, bf_hi(su.w), a7);
        sn += sii;

        float4 ca = *(const float4*)(cvec + 8 * qg);
        float4 cb = *(const float4*)(cvec + 8 * qg + 4);
        float4 ba = *(const float4*)(bias + 8 * qg);
        float4 bb = *(const float4*)(bias + 8 * qg + 4);
        float o0 = fmaxf(fmaf(sn, ca.x, a0) + ba.x, 0.f);
        float o1 = fmaxf(fmaf(sn, ca.y, a1) + ba.y, 0.f);
        float o2 = fmaxf(fmaf(sn, ca.z, a2) + ba.z, 0.f);
        float o3 = fmaxf(fmaf(sn, ca.w, a3) + ba.w, 0.f);
        float o4 = fmaxf(fmaf(sn, cb.x, a4) + bb.x, 0.f);
        float o5 = fmaxf(fmaf(sn, cb.y, a5) + bb.y, 0.f);
        float o6 = fmaxf(fmaf(sn, cb.z, a6) + bb.z, 0.f);
        float o7 = fmaxf(fmaf(sn, cb.w, a7) + bb.w, 0.f);

        if (h4 == 0) {
            uint4e o;
            o.x = (uint)f2bf(o0) | ((uint)f2bf(o1) << 16);
            o.y = (uint)f2bf(o2) | ((uint)f2bf(o3) << 16);
            o.z = (uint)f2bf(o4) | ((uint)f2bf(o5) << 16);
            o.w = (uint)f2bf(o6) | ((uint)f2bf(o7) << 16);
            int slot = qg ^ (nl & 7);
            *(uint4e*)(abase + nl * 256 + slot * 16) = o;
        }
    }

    __syncthreads();

    {
        int m = lane & 15, qm = lane >> 4;
        short8 afr[4];
        #pragma unroll
        for (int k0 = 0; k0 < 4; ++k0) {
            int slot = (qm + 4 * k0) ^ (m & 7);
            afr[k0] = *(const short8*)(abase + m * 256 + slot * 16);
        }
        floatx4 acc[2];
        #pragma unroll
        for (int u = 0; u < 2; ++u) { floatx4 z = {0.f, 0.f, 0.f, 0.f}; acc[u] = z; }
        #pragma unroll
        for (int u = 0; u < 2; ++u) {
            int nt = 2 * wv + u;
            #pragma unroll
            for (int k0 = 0; k0 < 4; ++k0) {
                short8 bfrag = *(const short8*)(Bp2 + ((size_t)(k0 * 4 + qm) * 128 + nt * 16 + m) * 8);
                acc[u] = __builtin_amdgcn_mfma_f32_16x16x32_bf16(afr[k0], bfrag, acc[u], 0, 0, 0);
            }
        }
        int orow_base = base + qm * 4;
        #pragma unroll
        for (int u = 0; u < 2; ++u) {
            int nt = 2 * wv + u;
            #pragma unroll
            for (int r = 0; r < 4; ++r)
                C[(size_t)(orow_base + r) * 128 + nt * 16 + m] = f2bf(acc[u][r]);
        }
    }
}

// ---------------- GCN aggregation (layer 2): one wave per dst node ----------------
__global__ __launch_bounds__(256) void agg_kernel(const ushort* __restrict__ hw,
                                                  const float* __restrict__ dis,
                                                  const int* __restrict__ cnt,
                                                  const ushort* __restrict__ bucket,
                                                  const uint* __restrict__ spack,
                                                  const uint* __restrict__ ovf,
                                                  const int* __restrict__ ovfcnt,
                                                  const float* __restrict__ cvec,
                                                  const float* __restrict__ bias,
                                                  ushort* __restrict__ out, int N) {
    __shared__ uint eds[4][64];
    int wv = threadIdx.x >> 6;
    int lane = threadIdx.x & 63;
    int q = lane & 15, h4 = lane >> 4;
    int i = blockIdx.x * 4 + wv;
    if (i >= N) return;
    int deg = cnt[i];
    int dmain = deg > 64 ? 64 : deg;
    const uint4* __restrict__ hv4 = (const uint4*)hw;

    uint ed = (uint)i;
    if (lane < dmain) ed = spack[bucket[(size_t)i * 64 + lane]];
    eds[wv][lane] = ed;

    float a0 = 0.f, a1 = 0.f, a2 = 0.f, a3 = 0.f;
    float a4 = 0.f, a5 = 0.f, a6 = 0.f, a7 = 0.f;
    float sn = 0.f;

    int dpad = (dmain + 15) & ~15;
    for (int j = 0; j < dpad; j += 16) {
        uint e0 = eds[wv][j + h4];
        uint e1 = eds[wv][j + 4 + h4];
        uint e2 = eds[wv][j + 8 + h4];
        uint e3 = eds[wv][j + 12 + h4];
        uint4 u0 = hv4[(size_t)(e0 & 0xffffu) * 16 + q];
        uint4 u1 = hv4[(size_t)(e1 & 0xffffu) * 16 + q];
        uint4 u2 = hv4[(size_t)(e2 & 0xffffu) * 16 + q];
        uint4 u3 = hv4[(size_t)(e3 & 0xffffu) * 16 + q];
        float n0 = __half2float(__ushort_as_half((ushort)(e0 >> 16)));
        float n1 = __half2float(__ushort_as_half((ushort)(e1 >> 16)));
        float n2 = __half2float(__ushort_as_half((ushort)(e2 >> 16)));
        float n3 = __half2float(__ushort_as_half((ushort)(e3 >> 16)));
        a0 = fmaf(n0, bf_lo(u0.x), a0); a1 = fmaf(n0, bf_hi(u0.x), a1);
        a2 = fmaf(n0, bf_lo(u0.y), a2); a3 = fmaf(n0, bf_hi(u0.y), a3);
        a4 = fmaf(n0, bf_lo(u0.z), a4); a5 = fmaf(n0, bf_hi(u0.z), a5);
        a6 = fmaf(n0, bf_lo(u0.w), a6); a7 = fmaf(n0, bf_hi(u0.w), a7);
        a0 = fmaf(n1, bf_lo(u1.x), a0); a1 = fmaf(n1, bf_hi(u1.x), a1);
        a2 = fmaf(n1, bf_lo(u1.y), a2); a3 = fmaf(n1, bf_hi(u1.y), a3);
        a4 = fmaf(n1, bf_lo(u1.z), a4); a5 = fmaf(n1, bf_hi(u1.z), a5);
        a6 = fmaf(n1, bf_lo(u1.w), a6); a7 = fmaf(n1, bf_hi(u1.w), a7);
        a0 = fmaf(n2, bf_lo(u2.x), a0); a1 = fmaf(n2, bf_hi(u2.x), a1);
        a2 = fmaf(n2, bf_lo(u2.y), a2); a3 = fmaf(n2, bf_hi(u2.y), a3);
        a4 = fmaf(n2, bf_lo(u2.z), a4); a5 = fmaf(n2, bf_hi(u2.z), a5);
        a6 = fmaf(n2, bf_lo(u2.w), a6); a7 = fmaf(n2, bf_hi(u2.w), a7);
        a0 = fmaf(n3, bf_lo(u3.x), a0); a1 = fmaf(n3, bf_hi(u3.x), a1);
        a2 = fmaf(n3, bf_lo(u3.y), a2); a3 = fmaf(n3, bf_hi(u3.y), a3);
        a4 = fmaf(n3, bf_lo(u3.z), a4); a5 = fmaf(n3, bf_hi(u3.z), a5);
        a6 = fmaf(n3, bf_lo(u3.w), a6); a7 = fmaf(n3, bf_hi(u3.w), a7);
        sn += (n0 + n1) + (n2 + n3);
    }
    if (deg > 64) {                        // overflow tail (wave-uniform, ~never)
        int ovfn = *ovfcnt;
        for (int k = 0; k < ovfn; ++k) {
            uint oe = ovf[k];
            if ((int)(oe & 0xffffu) == i && h4 == 0) {
                int s2 = (int)(oe >> 16);
                uint sp = spack[s2];
                float n0 = __half2float(__ushort_as_half((ushort)(sp >> 16)));
                uint4 u = hv4[(size_t)s2 * 16 + q];
                a0 = fmaf(n0, bf_lo(u.x), a0); a1 = fmaf(n0, bf_hi(u.x), a1);
                a2 = fmaf(n0, bf_lo(u.y), a2); a3 = fmaf(n0, bf_hi(u.y), a3);
                a4 = fmaf(n0, bf_lo(u.z), a4); a5 = fmaf(n0, bf_hi(u.z), a5);
                a6 = fmaf(n0, bf_lo(u.w), a6); a7 = fmaf(n0, bf_hi(u.w), a7);
                sn += n0;
            }
        }
    }

    a0 += __shfl_xor(a0, 16); a0 += __shfl_xor(a0, 32);
    a1 += __shfl_xor(a1, 16); a1 += __shfl_xor(a1, 32);
    a2 += __shfl_xor(a2, 16); a2 += __shfl_xor(a2, 32);
    a3 += __shfl_xor(a3, 16); a3 += __shfl_xor(a3, 32);
    a4 += __shfl_xor(a4, 16); a4 += __shfl_xor(a4, 32);
    a5 += __shfl_xor(a5, 16); a5 += __shfl_xor(a5, 32);
    a6 += __shfl_xor(a6, 16); a6 += __shfl_xor(a6, 32);
    a7 += __shfl_xor(a7, 16); a7 += __shfl_xor(a7, 32);
    sn += __shfl_xor(sn, 16); sn += __shfl_xor(sn, 32);

    // apply dis[i] (factored out of edge loop), then self-loop term
    float di = dis[i];
    float sii = di * di;
    a0 *= di; a1 *= di; a2 *= di; a3 *= di;
    a4 *= di; a5 *= di; a6 *= di; a7 *= di;
    sn *= di;
    uint4 su = hv4[(size_t)i * 16 + q];
    a0 = fmaf(sii, bf_lo(su.x), a0); a1 = fmaf(sii, bf_hi(su.x), a1);
    a2 = fmaf(sii, bf_lo(su.y), a2); a3 = fmaf(sii, bf_hi(su.y), a3);
    a4 = fmaf(sii, bf_lo(su.z), a4); a5 = fmaf(sii, bf_hi(su.z), a5);
    a6 = fmaf(sii, bf_lo(su.w), a6); a7 = fmaf(sii, bf_hi(su.w), a7);
    sn += sii;

    float c0 = 0.f, c1 = 0.f, c2 = 0.f, c3 = 0.f;
    float c4 = 0.f, c5 = 0.f, c6 = 0.f, c7 = 0.f;
    if (cvec) {
        float4 ca = *(const float4*)(cvec + 8 * q);
        float4 cb = *(const float4*)(cvec + 8 * q + 4);
        c0 = ca.x; c1 = ca.y; c2 = ca.z; c3 = ca.w;
        c4 = cb.x; c5 = cb.y; c6 = cb.z; c7 = cb.w;
    }
    float4 ba = *(const float4*)(bias + 8 * q);
    float4 bb = *(const float4*)(bias + 8 * q + 4);
    float o0 = fmaxf(fmaf(sn, c0, a0) + ba.x, 0.f);
    float o1 = fmaxf(fmaf(sn, c1, a1) + ba.y, 0.f);
    float o2 = fmaxf(fmaf(sn, c2, a2) + ba.z, 0.f);
    float o3 = fmaxf(fmaf(sn, c3, a3) + ba.w, 0.f);
    float o4 = fmaxf(fmaf(sn, c4, a4) + bb.x, 0.f);
    float o5 = fmaxf(fmaf(sn, c5, a5) + bb.y, 0.f);
    float o6 = fmaxf(fmaf(sn, c6, a6) + bb.z, 0.f);
    float o7 = fmaxf(fmaf(sn, c7, a7) + bb.w, 0.f);
    if (h4 == 0) {
        uint4 o;
        o.x = (uint)f2bf(o0) | ((uint)f2bf(o1) << 16);
        o.y = (uint)f2bf(o2) | ((uint)f2bf(o3) << 16);
        o.z = (uint)f2bf(o4) | ((uint)f2bf(o5) << 16);
        o.w = (uint)f2bf(o6) | ((uint)f2bf(o7) << 16);
        ((uint4*)out)[(size_t)i * 16 + q] = o;
    }
}

// ---------------- pool: 1024 blocks + LDS wave-combine (131K atomics, no fence) ----
__global__ __launch_bounds__(256) void pool_kernel(const ushort* __restrict__ h,
                                                   const int* __restrict__ glo,
                                                   float* __restrict__ pools) {
    __shared__ float spool[128];
    int t = threadIdx.x, c2 = t & 63, wv = t >> 6;
    int b = blockIdx.x;
    int g = b >> 6, ch = b & 63;
    int lo = glo[g], hi = glo[g + 1];
    int span = hi - lo;
    int chunk = (span + 63) >> 6;
    int r0 = lo + ch * chunk;
    int r1 = hi < r0 + chunk ? hi : r0 + chunk;
    const uint* __restrict__ hv = (const uint*)h;

    if (t < 128) spool[t] = 0.f;
    __syncthreads();

    float a0 = 0.f, a1 = 0.f;
    #pragma unroll 4
    for (int j = r0 + wv; j < r1; j += 4) {
        uint u = hv[(size_t)j * 64 + c2];
        a0 += bf_lo(u);
        a1 += bf_hi(u);
    }
    if (r0 < r1) {
        atomicAdd(&spool[2 * c2], a0);
        atomicAdd(&spool[2 * c2 + 1], a1);
    }
    __syncthreads();
    if (t < 128) {
        float v = spool[t];
        if (v != 0.f) atomicAdd(&pools[g * 128 + t], v);
    }
}

// ---------------- final MLP head: one block ----------------
__global__ __launch_bounds__(256) void final_kernel(const int* __restrict__ glo,
                                                    const float* __restrict__ pools,
                                                    const float* __restrict__ Wf1,
                                                    const float* __restrict__ bf1,
                                                    const float* __restrict__ Wf2,
                                                    const float* __restrict__ bf2,
                                                    float* __restrict__ out) {
    __shared__ float pooled[16][128];
    __shared__ float z[16][64];
    int t = threadIdx.x;
    for (int idx = t; idx < 2048; idx += 256) {
        int gg = idx >> 7, c = idx & 127;
        int cn = glo[gg + 1] - glo[gg];
        float cnf = (float)(cn > 1 ? cn : 1);
        pooled[gg][c] = pools[idx] / cnf;
    }
    __syncthreads();
    for (int idx = t; idx < 1024; idx += 256) {
        int gg = idx >> 6, j = idx & 63;
        float s = bf1[j];
        for (int k = 0; k < 128; ++k) s = fmaf(pooled[gg][k], Wf1[k * 64 + j], s);
        z[gg][j] = fmaxf(s, 0.f);
    }
    __syncthreads();
    if (t < 160) {
        int gg = t / 10, k = t % 10;
        float s = bf2[k];
        for (int j = 0; j < 64; ++j) s = fmaf(z[gg][j], Wf2[j * 10 + k], s);
        out[t] = s;
    }
}

// ---------------- launch ----------------

extern "C" void kernel_launch(void* const* d_in, const int* in_sizes, int n_in,
                              void* d_out, int out_size, void* d_ws, size_t ws_size,
                              hipStream_t stream) {
    const float* x    = (const float*)d_in[0];
    const int* edge   = (const int*)d_in[1];   // [2,E]: src then dst
    const int* batch  = (const int*)d_in[2];
    const float* W_in = (const float*)d_in[3];
    const float* b_in = (const float*)d_in[4];
    const float* W1   = (const float*)d_in[5];
    const float* b1   = (const float*)d_in[6];
    const float* W2   = (const float*)d_in[7];
    const float* b2   = (const float*)d_in[8];
    const float* Wf1  = (const float*)d_in[9];
    const float* bf1  = (const float*)d_in[10];
    const float* Wf2  = (const float*)d_in[11];
    const float* bf2  = (const float*)d_in[12];
    float* out = (float*)d_out;

    char* ws = (char*)d_ws;
    size_t off = 0;
    auto alloc = [&](size_t bytes) -> void* {
        void* p = ws + off;
        off += (bytes + 511) & ~(size_t)511;
        return p;
    };
    // zero region: cnt + pools + {ovfcnt, glo[17]} -> one memset
    int* cnt      = (int*)alloc((size_t)NN * 4);
    float* pools  = (float*)alloc(16 * 128 * 4);
    int* misc     = (int*)alloc(512);
    size_t zero_bytes = off;
    int* ovfcnt   = misc;
    int* glo      = misc + 8;                      // 17 ints
    ushort* bufA  = (ushort*)alloc((size_t)NN * 128 * 2);   // hw1 = x@(W_in@W1)
    ushort* bufB  = (ushort*)alloc((size_t)NN * 128 * 2);   // h2 (layer-2 out)
    ushort* bufC  = (ushort*)alloc((size_t)NN * 128 * 2);   // hw2 = h1@W2
    ushort* Bp1   = (ushort*)alloc(128 * 128 * 2);
    ushort* Bp2   = (ushort*)alloc(128 * 128 * 2);
    float* cvec   = (float*)alloc(128 * 4);
    float* dis    = (float*)alloc((size_t)NN * 4);
    uint* spack   = (uint*)alloc((size_t)NN * 4);
    ushort* bucket= (ushort*)alloc((size_t)NN * 64 * 2);    // 5.12 MB
    uint* ovf     = (uint*)alloc((size_t)EE * 4);           // overflow (d | s<<16)

    hipMemsetAsync(cnt, 0, zero_bytes, stream);

    prep_kernel<<<129, 256, 0, stream>>>(W_in, W1, b_in, W2, batch, Bp1, Bp2, cvec, glo);
    fill_kernel<<<313 + NN / 64, 256, 0, stream>>>(edge, edge + EE, cnt, ovfcnt, ovf,
                                                   bucket, x, Bp1, bufA);
    dsprep_kernel<<<NCH, 256, 0, stream>>>(cnt, dis, spack, NN);
    agg1m_kernel<<<NN / 16, 256, 0, stream>>>(bufA, dis, cnt, bucket, spack, ovf, ovfcnt,
                                              cvec, b1, Bp2, bufC);
    agg_kernel<<<NN / 4, 256, 0, stream>>>(bufC, dis, cnt, bucket, spack, ovf, ovfcnt,
                                           nullptr, b2, bufB, NN);
    pool_kernel<<<1024, 256, 0, stream>>>(bufB, glo, pools);
    final_kernel<<<1, 256, 0, stream>>>(glo, pools, Wf1, bf1, Wf2, bf2, out);
}